// Round 4
// baseline (2152.643 us; speedup 1.0000x reference)
//
#include <hip/hip_runtime.h>

// GLA forward, f32. Algebraic structure:
//  - MPGA collapses: fm = mask ? foreground : (Wv_f @ mean(background) + bv_f)
//  - patch GAP collapses to rank-1: t[n,o] = Wq_p@r + bq_p*Ssum with global
//    fields Sg (scalar) and Vg (per-channel) over the padded background.
//  - att == 0 for patches whose 3x3 mask window is nonzero (mm gating).
// Memory plan (~105 MB of d_ws): score pipeline runs per-batch through one
//  single-sample cr buffer:  [ Ak | Bim(=Pb later) | mmf | smalls | cr ]

#define BSZ 2
#define C 64
#define WD 64
#define WH 4096           // 64*64
#define PW 66
#define PP 4356           // 66*66
#define KC 576            // C*9
#define NP 4096           // patches per sample

// ---------------- small prep kernels ----------------

__global__ void k_prep(const float* __restrict__ Wk_p, const float* __restrict__ bk_p,
                       float* __restrict__ u, float* __restrict__ bks) {
  int c = threadIdx.x;
  float s = 0.f;
  for (int o = 0; o < C; ++o) s += Wk_p[o * C + c];
  u[c] = s;
  if (c == 0) {
    float t = 0.f;
    for (int o = 0; o < C; ++o) t += bk_p[o];
    bks[0] = t;
  }
}

// mu[b][c] = mean over w*h of background
__global__ void k_mu(const float* __restrict__ fg, const float* __restrict__ mask,
                     float* __restrict__ mu) {
  int bc = blockIdx.x;  // b*64+c
  int b = bc >> 6;
  const float* f = fg + (size_t)bc * WH;
  const float* mk = mask + (size_t)b * WH;
  float sum = 0.f;
  for (int i = threadIdx.x; i < WH; i += 256) sum += f[i] * (1.f - mk[i]);
  __shared__ float red[256];
  red[threadIdx.x] = sum;
  __syncthreads();
  for (int s = 128; s > 0; s >>= 1) {
    if (threadIdx.x < s) red[threadIdx.x] += red[threadIdx.x + s];
    __syncthreads();
  }
  if (threadIdx.x == 0) mu[bc] = red[0] / (float)WH;
}

__global__ void k_vmean(const float* __restrict__ Wv_f, const float* __restrict__ bv_f,
                        const float* __restrict__ mu, float* __restrict__ vmean) {
  int t = threadIdx.x;  // 0..127
  int b = t >> 6, c = t & 63;
  float acc = bv_f[c];
  for (int cc = 0; cc < C; ++cc) acc += Wv_f[c * C + cc] * mu[b * C + cc];
  vmean[t] = acc;
}

// fm = fg*mask + (1-mask)*vmean
__global__ void k_fm(const float* __restrict__ fg, const float* __restrict__ mask,
                     const float* __restrict__ vmean, float* __restrict__ fm) {
  int idx = blockIdx.x * 256 + threadIdx.x;
  if (idx >= BSZ * C * WH) return;
  int b = idx >> 18;
  int c = (idx >> 12) & 63;
  int pos = idx & (WH - 1);
  float m = mask[b * WH + pos];
  fm[idx] = fg[idx] * m + (1.f - m) * vmean[b * C + c];
}

// bgp[b][pos=66*66][c] = padded background + 1e-7 (transposed layout)
__global__ void k_bgpT(const float* __restrict__ fg, const float* __restrict__ mask,
                       float* __restrict__ bgp) {
  int b = blockIdx.y, xp = blockIdx.x;  // xp: 0..65
  float* out = bgp + ((size_t)b * PP + (size_t)xp * PW) * C;
  int t = threadIdx.x;
  __shared__ float tile[64][65];
  int xi = xp - 1;
  if (xi >= 0 && xi < WD) {
    const float* fgb = fg + (size_t)b * C * WH + (size_t)xi * WD;
    const float* mkb = mask + (size_t)b * WH + (size_t)xi * WD;
    for (int i = t; i < 64 * 64; i += 256) {
      int c = i >> 6, y = i & 63;
      tile[c][y] = fgb[(size_t)c * WH + y] * (1.f - mkb[y]);
    }
  }
  __syncthreads();
  for (int i = t; i < PW * C; i += 256) {
    int yp = i >> 6, c = i & 63;
    float v = 1e-7f;
    int yj = yp - 1;
    if (xi >= 0 && xi < WD && yj >= 0 && yj < WD) v += tile[c][yj];
    out[(size_t)yp * C + c] = v;
  }
}

// Vg[b][pos][o] = Wv_p @ bgp[pos,:] + bv_p
__global__ void k_vgT(const float* __restrict__ bgp, const float* __restrict__ Wv_p,
                      const float* __restrict__ bv_p, float* __restrict__ Vg) {
  __shared__ float Wt[64][65];   // Wt[c][o]
  __shared__ float bgl[4][64];
  int t = threadIdx.x;
  for (int i = t; i < 4096; i += 256) Wt[i & 63][i >> 6] = Wv_p[i];
  int pos0 = blockIdx.x * 4;
  {
    int p2 = t >> 6, c = t & 63;
    int gp = pos0 + p2;
    bgl[p2][c] = (gp < BSZ * PP) ? bgp[(size_t)gp * C + c] : 0.f;
  }
  __syncthreads();
  int pi = t >> 6, o = t & 63;
  int gpos = pos0 + pi;
  if (gpos < BSZ * PP) {
    float acc = bv_p[o];
    for (int c = 0; c < 64; ++c) acc += Wt[c][o] * bgl[pi][c];
    Vg[(size_t)gpos * C + o] = acc;
  }
}

// Sg[b][pos] = u @ bgp[pos,:] + bksum
__global__ void k_sgT(const float* __restrict__ bgp, const float* __restrict__ u,
                      const float* __restrict__ bks, float* __restrict__ Sg) {
  int t = threadIdx.x;
  int lane = t & 63, w = t >> 6;
  int gpos = blockIdx.x * 4 + w;
  if (gpos >= BSZ * PP) return;
  float v = u[lane] * bgp[(size_t)gpos * C + lane];
#pragma unroll
  for (int off = 32; off > 0; off >>= 1) v += __shfl_down(v, off, 64);
  if (lane == 0) Sg[gpos] = v + bks[0];
}

// ------------- per-patch GAP + L2 normalize -> Ak[n][k], mmf -------------
__global__ void k_gap(const float* __restrict__ bgp, const float* __restrict__ mask,
                      const float* __restrict__ Sg, const float* __restrict__ Vg,
                      const float* __restrict__ Wq_p, const float* __restrict__ bq_p,
                      const float* __restrict__ gamma,
                      float* __restrict__ Ak, float* __restrict__ mmf) {
  int bn = blockIdx.x;
  int b = bn >> 12, n = bn & 4095;
  int x = n >> 6, y = n & 63;
  int c = threadIdx.x;  // one wave (64)
  const float* bg = bgp + (size_t)b * PP * C;
  const float* sg = Sg + (size_t)b * PP;
  float ckp[9], m[9];
  float z = 0.f, Ssum = 0.f, r = 0.f;
#pragma unroll
  for (int p = 0; p < 9; ++p) {
    int di = p / 3, dj = p % 3;
    int xp = x + di, yp = y + dj;  // padded coords
    ckp[p] = bg[(size_t)(xp * PW + yp) * C + c];
    int xi = xp - 1, yj = yp - 1;
    float mv = 0.f;
    if (xi >= 0 && xi < WD && yj >= 0 && yj < WD) mv = mask[b * WH + xi * WD + yj];
    m[p] = mv;
    z += mv;
    float sv = sg[xp * PW + yp];
    Ssum += sv;
    r += ckp[p] * sv;
  }
  __shared__ float rs[64];
  rs[c] = r;
  __syncthreads();
  float t = bq_p[c] * Ssum;
  for (int cc = 0; cc < C; ++cc) t += Wq_p[c * C + cc] * rs[cc];
  float mx = fmaxf(t, 0.f);
  float e1 = __expf(t - mx), e0 = __expf(-mx);
  float denom = z * e1 + (9.f - z) * e0;
  float coef = gamma[0] * e0 / denom;
  const float* vg = Vg + (size_t)b * PP * C;
  float outv[9], ss = 0.f;
#pragma unroll
  for (int p = 0; p < 9; ++p) {
    int di = p / 3, dj = p % 3;
    float v = coef * vg[(size_t)((x + di) * PW + (y + dj)) * C + c];
    float o = (m[p] > 0.f) ? ckp[p] : v;
    outv[p] = o;
    ss += o * o;
  }
#pragma unroll
  for (int off = 32; off > 0; off >>= 1) ss += __shfl_down(ss, off, 64);
  ss = __shfl(ss, 0, 64);
  float rn = 1.f / sqrtf(ss);
  float* ak = Ak + ((size_t)b * NP + n) * KC + c * 9;
#pragma unroll
  for (int p = 0; p < 9; ++p) ak[p] = outv[p] * rn;
  if (c == 0) mmf[b * NP + n] = (z == 0.f) ? 1.f : 0.f;
}

// Bim[b][k=(c,di,dj)][xy] = fm zero-padded patch element
__global__ void k_im2col(const float* __restrict__ fm, float* __restrict__ Bim) {
  int idx = blockIdx.x * 256 + threadIdx.x;
  if (idx >= BSZ * KC * WH) return;
  int b = idx / (KC * WH);
  int rem = idx - b * (KC * WH);
  int k = rem >> 12, xy = rem & 4095;
  int c = k / 9, p = k - c * 9;
  int di = p / 3, dj = p - di * 3;
  int x = xy >> 6, y = xy & 63;
  int xi = x + di - 1, yj = y + dj - 1;
  float v = 0.f;
  if (xi >= 0 && xi < WD && yj >= 0 && yj < WD)
    v = fm[((size_t)(b * C + c)) * WH + xi * WD + yj];
  Bim[idx] = v;
}

// ---------------- tiled f32 GEMMs (single-sample pointers) ----------------
#define BM 64
#define BN 64
#define BK 16

// cr[n][xy] = sum_k A[n][k] * Bp[k][xy]   (A: [NP][KC], Bp: [KC][WH])
__global__ __launch_bounds__(256) void k_gemm1(const float* __restrict__ A,
                                               const float* __restrict__ Bp,
                                               float* __restrict__ Cp) {
  int m0 = blockIdx.y * BM;  // n (patch) tile
  int n0 = blockIdx.x * BN;  // xy tile
  __shared__ __align__(16) float As[BK][BM + 4];
  __shared__ __align__(16) float Bs[BK][BN + 4];
  int t = threadIdx.x;
  int tn = t & 15, tm = t >> 4;
  float acc[4][4] = {};
  for (int k0 = 0; k0 < KC; k0 += BK) {
    {
      int m = t >> 2, kq = (t & 3) << 2;
      const float4 v = *reinterpret_cast<const float4*>(A + (size_t)(m0 + m) * KC + k0 + kq);
      As[kq + 0][m] = v.x; As[kq + 1][m] = v.y; As[kq + 2][m] = v.z; As[kq + 3][m] = v.w;
    }
    {
      int r = t >> 4, c4 = (t & 15) << 2;
      *reinterpret_cast<float4*>(&Bs[r][c4]) =
          *reinterpret_cast<const float4*>(Bp + (size_t)(k0 + r) * WH + n0 + c4);
    }
    __syncthreads();
#pragma unroll
    for (int kk = 0; kk < BK; ++kk) {
      float4 a = *reinterpret_cast<const float4*>(&As[kk][tm * 4]);
      float4 bb = *reinterpret_cast<const float4*>(&Bs[kk][tn * 4]);
      float av[4] = {a.x, a.y, a.z, a.w};
      float bv[4] = {bb.x, bb.y, bb.z, bb.w};
#pragma unroll
      for (int i = 0; i < 4; ++i)
#pragma unroll
        for (int j = 0; j < 4; ++j) acc[i][j] += av[i] * bv[j];
    }
    __syncthreads();
  }
#pragma unroll
  for (int i = 0; i < 4; ++i) {
    float4 w = {acc[i][0], acc[i][1], acc[i][2], acc[i][3]};
    *reinterpret_cast<float4*>(Cp + (size_t)(m0 + tm * 4 + i) * WH + n0 + tn * 4) = w;
  }
}

// P[k2][xy] = sum_n A[n][k2] * att[n][xy]   (A: [NP][KC], att: [NP][WH])
__global__ __launch_bounds__(256) void k_gemm2(const float* __restrict__ A,
                                               const float* __restrict__ Bp,
                                               float* __restrict__ Cp) {
  int m0 = blockIdx.y * BM;  // k2 tile (9 tiles of 64 -> 576)
  int n0 = blockIdx.x * BN;  // xy tile
  __shared__ __align__(16) float As[BK][BM + 4];
  __shared__ __align__(16) float Bs[BK][BN + 4];
  int t = threadIdx.x;
  int tn = t & 15, tm = t >> 4;
  float acc[4][4] = {};
  for (int k0 = 0; k0 < NP; k0 += BK) {
    int r = t >> 4, c4 = (t & 15) << 2;
    *reinterpret_cast<float4*>(&As[r][c4]) =
        *reinterpret_cast<const float4*>(A + (size_t)(k0 + r) * KC + m0 + c4);
    *reinterpret_cast<float4*>(&Bs[r][c4]) =
        *reinterpret_cast<const float4*>(Bp + (size_t)(k0 + r) * WH + n0 + c4);
    __syncthreads();
#pragma unroll
    for (int kk = 0; kk < BK; ++kk) {
      float4 a = *reinterpret_cast<const float4*>(&As[kk][tm * 4]);
      float4 bb = *reinterpret_cast<const float4*>(&Bs[kk][tn * 4]);
      float av[4] = {a.x, a.y, a.z, a.w};
      float bv[4] = {bb.x, bb.y, bb.z, bb.w};
#pragma unroll
      for (int i = 0; i < 4; ++i)
#pragma unroll
        for (int j = 0; j < 4; ++j) acc[i][j] += av[i] * bv[j];
    }
    __syncthreads();
  }
#pragma unroll
  for (int i = 0; i < 4; ++i) {
    float4 w = {acc[i][0], acc[i][1], acc[i][2], acc[i][3]};
    *reinterpret_cast<float4*>(Cp + (size_t)(m0 + tm * 4 + i) * WH + n0 + tn * 4) = w;
  }
}

// ---------------- box filter (in-place, per-patch-row LDS) ----------------
__global__ __launch_bounds__(256) void k_box(float* __restrict__ cr) {
  __shared__ __align__(16) float sIn[WH];
  __shared__ __align__(16) float sT[WH];
  float* row = cr + (size_t)blockIdx.x * WH;
  const float4* r4 = reinterpret_cast<const float4*>(row);
  float4* s4 = reinterpret_cast<float4*>(sIn);
  for (int i = threadIdx.x; i < WH / 4; i += 256) s4[i] = r4[i];
  __syncthreads();
  for (int i = threadIdx.x; i < WH; i += 256) {
    int y = i & 63;
    float v = sIn[i];
    if (y > 0) v += sIn[i - 1];
    if (y < 63) v += sIn[i + 1];
    sT[i] = v;
  }
  __syncthreads();
  for (int i = threadIdx.x; i < WH; i += 256) {
    int x = i >> 6;
    float v = sT[i];
    if (x > 0) v += sT[i - 64];
    if (x < 63) v += sT[i + 64];
    row[i] = v;
  }
}

// ---------------- column softmax over n (in-place, mm-gated) ----------------
__global__ __launch_bounds__(256) void k_csoftmax(const float* __restrict__ mm,
                                                  float* __restrict__ cr) {
  int col = threadIdx.x & 31, seg = threadIdx.x >> 5;  // 32 cols x 8 segs
  int xy = blockIdx.x * 32 + col;
  float* colp = cr + xy;
  const int SEGN = NP / 8;  // 512
  int n0 = seg * SEGN;
  float mx = -3.4e38f, s = 0.f;
  int nl = 0;
  for (int n = n0; n < n0 + SEGN; ++n) {
    if (mm[n] != 0.f) {
      float v = colp[(size_t)n * WH];
      float m2 = fmaxf(mx, v);
      s = s * __expf(mx - m2) + __expf(v - m2);
      mx = m2;
      ++nl;
    }
  }
  __shared__ float pm[8][32], ps[8][32];
  __shared__ int pn[8][32];
  __shared__ float fm2[32], finv[32];
  pm[seg][col] = mx;
  ps[seg][col] = s;
  pn[seg][col] = nl;
  __syncthreads();
  if (seg == 0) {
    float M = -3.4e38f;
    int NL = 0;
    for (int k = 0; k < 8; ++k) {
      M = fmaxf(M, pm[k][col]);
      NL += pn[k][col];
    }
    float S = 0.f;
    if (M > -3.0e38f)
      for (int k = 0; k < 8; ++k) S += ps[k][col] * __expf(pm[k][col] - M);
    int nm = NP - NL;
    float m2 = (nm > 0) ? fmaxf(M, 0.f) : M;
    float denom = (M > -3.0e38f ? S * __expf(M - m2) : 0.f) + (float)nm * __expf(-m2);
    fm2[col] = m2;
    finv[col] = 1.f / denom;
  }
  __syncthreads();
  float m2 = fm2[col], inv = finv[col];
  for (int n = n0; n < n0 + SEGN; ++n) {
    float v = (mm[n] != 0.f) ? __expf(colp[(size_t)n * WH] - m2) * inv : 0.f;
    colp[(size_t)n * WH] = v;
  }
}

// rec[b][c][x][y] = sum_{i,j} P[b][(c,i,j)][x+1-i, y+1-j]
__global__ void k_rec(const float* __restrict__ P, float* __restrict__ out) {
  int idx = blockIdx.x * 256 + threadIdx.x;
  if (idx >= BSZ * C * WH) return;
  int b = idx >> 18;
  int r = idx & 262143;
  int c = r >> 12;
  int xy = r & 4095;
  int x = xy >> 6, y = xy & 63;
  const float* Pb = P + (size_t)b * KC * WH;
  float acc = 0.f;
#pragma unroll
  for (int i = 0; i < 3; ++i) {
    int xp = x + 1 - i;
    if (xp < 0 || xp >= WD) continue;
#pragma unroll
    for (int j = 0; j < 3; ++j) {
      int yp = y + 1 - j;
      if (yp < 0 || yp >= WD) continue;
      acc += Pb[(size_t)(c * 9 + i * 3 + j) * WH + xp * WD + yp];
    }
  }
  out[idx] = acc;
}

// ---------------- launcher ----------------

extern "C" void kernel_launch(void* const* d_in, const int* in_sizes, int n_in,
                              void* d_out, int out_size, void* d_ws, size_t ws_size,
                              hipStream_t stream) {
  const float* fg    = (const float*)d_in[0];
  const float* mask  = (const float*)d_in[1];
  // d_in[2] same_number_of_args unused; Wq_f/bq_f/Wk_f/bk_f (3..6) are dead inputs.
  const float* Wv_f  = (const float*)d_in[7];
  const float* bv_f  = (const float*)d_in[8];
  const float* Wq_p  = (const float*)d_in[9];
  const float* bq_p  = (const float*)d_in[10];
  const float* Wk_p  = (const float*)d_in[11];
  const float* bk_p  = (const float*)d_in[12];
  const float* Wv_p  = (const float*)d_in[13];
  const float* bv_p  = (const float*)d_in[14];
  const float* gamma = (const float*)d_in[15];

  float* ws = (float*)d_ws;
  size_t off = 0;
  auto alloc = [&](size_t n) { size_t o = off; off += (n + 63) & ~(size_t)63; return o; };
  float* Ak  = ws + alloc((size_t)BSZ * NP * KC);   //  4,718,592
  float* Bim = ws + alloc((size_t)BSZ * KC * WH);   //  4,718,592 (Pb aliases later)
  float* mmf = ws + alloc((size_t)BSZ * NP);        //  8,192
  float* mu  = ws + alloc(BSZ * C);
  float* vmn = ws + alloc(BSZ * C);
  float* u   = ws + alloc(C);
  float* bks = ws + alloc(64);
  float* cr  = ws + alloc((size_t)NP * WH);         // 16,777,216 (single sample)
  // prep fields alias the head of cr (all dead before k_gemm1 writes cr):
  size_t poff = 0;
  auto palloc = [&](size_t n) { size_t o = poff; poff += (n + 63) & ~(size_t)63; return o; };
  float* bgp = cr + palloc((size_t)BSZ * PP * C);   // 557,568
  float* Vg  = cr + palloc((size_t)BSZ * PP * C);   // 557,568
  float* Sg  = cr + palloc((size_t)BSZ * PP);       // 8,712
  float* fmb = cr + palloc((size_t)BSZ * C * WH);   // 524,288
  float* Pb  = Bim;  // gemm2 output aliases Bim (dead after gemm1)
  (void)ws_size; (void)in_sizes; (void)n_in; (void)out_size;

  k_prep<<<1, 64, 0, stream>>>(Wk_p, bk_p, u, bks);
  k_mu<<<BSZ * C, 256, 0, stream>>>(fg, mask, mu);
  k_vmean<<<1, 128, 0, stream>>>(Wv_f, bv_f, mu, vmn);
  k_fm<<<(BSZ * C * WH + 255) / 256, 256, 0, stream>>>(fg, mask, vmn, fmb);
  k_bgpT<<<dim3(PW, BSZ), 256, 0, stream>>>(fg, mask, bgp);
  k_vgT<<<(BSZ * PP + 3) / 4, 256, 0, stream>>>(bgp, Wv_p, bv_p, Vg);
  k_sgT<<<(BSZ * PP + 3) / 4, 256, 0, stream>>>(bgp, u, bks, Sg);
  k_gap<<<BSZ * NP, 64, 0, stream>>>(bgp, mask, Sg, Vg, Wq_p, bq_p, gamma, Ak, mmf);
  k_im2col<<<(BSZ * KC * WH + 255) / 256, 256, 0, stream>>>(fmb, Bim);
  for (int b = 0; b < BSZ; ++b) {
    const float* Akb = Ak + (size_t)b * NP * KC;
    k_gemm1<<<dim3(WH / BN, NP / BM), 256, 0, stream>>>(Akb, Bim + (size_t)b * KC * WH, cr);
    k_box<<<NP, 256, 0, stream>>>(cr);
    k_csoftmax<<<WH / 32, 256, 0, stream>>>(mmf + (size_t)b * NP, cr);
    k_gemm2<<<dim3(WH / BN, KC / BM), 256, 0, stream>>>(Akb, cr, Pb + (size_t)b * KC * WH);
  }
  k_rec<<<(BSZ * C * WH + 255) / 256, 256, 0, stream>>>(Pb, (float*)d_out);
}

// Round 6
// 1335.314 us; speedup vs baseline: 1.6121x; 1.6121x over previous
//
#include <hip/hip_runtime.h>

// GLA forward, f32. Algebraic structure:
//  - MPGA collapses: fm = mask ? foreground : (Wv_f @ mean(background) + bv_f)
//  - patch GAP collapses to rank-1 via global fields Sg, Vg.
//  - att rows for patches overlapping the mask are exactly 0 -> compaction:
//    only nlive (~2940/4096) rows flow through gemm1/box/softmax/gemm2.
// Softmax over n is per-xy-column: one THREAD per column, coalesced row-major.

#define BSZ 2
#define C 64
#define WD 64
#define WH 4096           // 64*64
#define PW 66
#define PP 4356           // 66*66
#define KC 576            // C*9
#define NP 4096           // patches per sample

// ---------------- small prep kernels ----------------

__global__ void k_prep(const float* __restrict__ Wk_p, const float* __restrict__ bk_p,
                       float* __restrict__ u, float* __restrict__ bks) {
  int c = threadIdx.x;
  float s = 0.f;
  for (int o = 0; o < C; ++o) s += Wk_p[o * C + c];
  u[c] = s;
  if (c == 0) {
    float t = 0.f;
    for (int o = 0; o < C; ++o) t += bk_p[o];
    bks[0] = t;
  }
}

__global__ void k_mu(const float* __restrict__ fg, const float* __restrict__ mask,
                     float* __restrict__ mu) {
  int bc = blockIdx.x;  // b*64+c
  int b = bc >> 6;
  const float* f = fg + (size_t)bc * WH;
  const float* mk = mask + (size_t)b * WH;
  float sum = 0.f;
  for (int i = threadIdx.x; i < WH; i += 256) sum += f[i] * (1.f - mk[i]);
  __shared__ float red[256];
  red[threadIdx.x] = sum;
  __syncthreads();
  for (int s = 128; s > 0; s >>= 1) {
    if (threadIdx.x < s) red[threadIdx.x] += red[threadIdx.x + s];
    __syncthreads();
  }
  if (threadIdx.x == 0) mu[bc] = red[0] / (float)WH;
}

__global__ void k_vmean(const float* __restrict__ Wv_f, const float* __restrict__ bv_f,
                        const float* __restrict__ mu, float* __restrict__ vmean) {
  int t = threadIdx.x;  // 0..127
  int b = t >> 6, c = t & 63;
  float acc = bv_f[c];
  for (int cc = 0; cc < C; ++cc) acc += Wv_f[c * C + cc] * mu[b * C + cc];
  vmean[t] = acc;
}

__global__ void k_fm(const float* __restrict__ fg, const float* __restrict__ mask,
                     const float* __restrict__ vmean, float* __restrict__ fm) {
  int idx = blockIdx.x * 256 + threadIdx.x;
  if (idx >= BSZ * C * WH) return;
  int b = idx >> 18;
  int c = (idx >> 12) & 63;
  int pos = idx & (WH - 1);
  float m = mask[b * WH + pos];
  fm[idx] = fg[idx] * m + (1.f - m) * vmean[b * C + c];
}

// bgp[b][pos=66*66][c] = padded background + 1e-7 (transposed layout)
__global__ void k_bgpT(const float* __restrict__ fg, const float* __restrict__ mask,
                       float* __restrict__ bgp) {
  int b = blockIdx.y, xp = blockIdx.x;  // xp: 0..65
  float* out = bgp + ((size_t)b * PP + (size_t)xp * PW) * C;
  int t = threadIdx.x;
  __shared__ float tile[64][65];
  int xi = xp - 1;
  if (xi >= 0 && xi < WD) {
    const float* fgb = fg + (size_t)b * C * WH + (size_t)xi * WD;
    const float* mkb = mask + (size_t)b * WH + (size_t)xi * WD;
    for (int i = t; i < 64 * 64; i += 256) {
      int c = i >> 6, y = i & 63;
      tile[c][y] = fgb[(size_t)c * WH + y] * (1.f - mkb[y]);
    }
  }
  __syncthreads();
  for (int i = t; i < PW * C; i += 256) {
    int yp = i >> 6, c = i & 63;
    float v = 1e-7f;
    int yj = yp - 1;
    if (xi >= 0 && xi < WD && yj >= 0 && yj < WD) v += tile[c][yj];
    out[(size_t)yp * C + c] = v;
  }
}

// Vg[b][pos][o] = Wv_p @ bgp[pos,:] + bv_p
__global__ void k_vgT(const float* __restrict__ bgp, const float* __restrict__ Wv_p,
                      const float* __restrict__ bv_p, float* __restrict__ Vg) {
  __shared__ float Wt[64][65];   // Wt[c][o]
  __shared__ float bgl[4][64];
  int t = threadIdx.x;
  for (int i = t; i < 4096; i += 256) Wt[i & 63][i >> 6] = Wv_p[i];
  int pos0 = blockIdx.x * 4;
  {
    int p2 = t >> 6, c = t & 63;
    int gp = pos0 + p2;
    bgl[p2][c] = (gp < BSZ * PP) ? bgp[(size_t)gp * C + c] : 0.f;
  }
  __syncthreads();
  int pi = t >> 6, o = t & 63;
  int gpos = pos0 + pi;
  if (gpos < BSZ * PP) {
    float acc = bv_p[o];
    for (int c = 0; c < 64; ++c) acc += Wt[c][o] * bgl[pi][c];
    Vg[(size_t)gpos * C + o] = acc;
  }
}

// Sg[b][pos] = u @ bgp[pos,:] + bksum
__global__ void k_sgT(const float* __restrict__ bgp, const float* __restrict__ u,
                      const float* __restrict__ bks, float* __restrict__ Sg) {
  int t = threadIdx.x;
  int lane = t & 63, w = t >> 6;
  int gpos = blockIdx.x * 4 + w;
  if (gpos >= BSZ * PP) return;
  float v = u[lane] * bgp[(size_t)gpos * C + lane];
#pragma unroll
  for (int off = 32; off > 0; off >>= 1) v += __shfl_down(v, off, 64);
  if (lane == 0) Sg[gpos] = v + bks[0];
}

// ------------- per-patch GAP + L2 normalize -> Ak[n][k], mmf -------------
__global__ void k_gap(const float* __restrict__ bgp, const float* __restrict__ mask,
                      const float* __restrict__ Sg, const float* __restrict__ Vg,
                      const float* __restrict__ Wq_p, const float* __restrict__ bq_p,
                      const float* __restrict__ gamma,
                      float* __restrict__ Ak, float* __restrict__ mmf) {
  int bn = blockIdx.x;
  int b = bn >> 12, n = bn & 4095;
  int x = n >> 6, y = n & 63;
  int c = threadIdx.x;  // one wave (64)
  const float* bg = bgp + (size_t)b * PP * C;
  const float* sg = Sg + (size_t)b * PP;
  float ckp[9], m[9];
  float z = 0.f, Ssum = 0.f, r = 0.f;
#pragma unroll
  for (int p = 0; p < 9; ++p) {
    int di = p / 3, dj = p % 3;
    int xp = x + di, yp = y + dj;  // padded coords
    ckp[p] = bg[(size_t)(xp * PW + yp) * C + c];
    int xi = xp - 1, yj = yp - 1;
    float mv = 0.f;
    if (xi >= 0 && xi < WD && yj >= 0 && yj < WD) mv = mask[b * WH + xi * WD + yj];
    m[p] = mv;
    z += mv;
    float sv = sg[xp * PW + yp];
    Ssum += sv;
    r += ckp[p] * sv;
  }
  __shared__ float rs[64];
  rs[c] = r;
  __syncthreads();
  float t = bq_p[c] * Ssum;
  for (int cc = 0; cc < C; ++cc) t += Wq_p[c * C + cc] * rs[cc];
  float mx = fmaxf(t, 0.f);
  float e1 = __expf(t - mx), e0 = __expf(-mx);
  float denom = z * e1 + (9.f - z) * e0;
  float coef = gamma[0] * e0 / denom;
  const float* vg = Vg + (size_t)b * PP * C;
  float outv[9], ss = 0.f;
#pragma unroll
  for (int p = 0; p < 9; ++p) {
    int di = p / 3, dj = p % 3;
    float v = coef * vg[(size_t)((x + di) * PW + (y + dj)) * C + c];
    float o = (m[p] > 0.f) ? ckp[p] : v;
    outv[p] = o;
    ss += o * o;
  }
#pragma unroll
  for (int off = 32; off > 0; off >>= 1) ss += __shfl_down(ss, off, 64);
  ss = __shfl(ss, 0, 64);
  float rn = 1.f / sqrtf(ss);
  float* ak = Ak + ((size_t)b * NP + n) * KC + c * 9;
#pragma unroll
  for (int p = 0; p < 9; ++p) ak[p] = outv[p] * rn;
  if (c == 0) mmf[b * NP + n] = (z == 0.f) ? 1.f : 0.f;
}

// ---- live-patch compaction: prefix-sum over mmf -> lividx (padded w/ 0), nliv
__global__ void k_scan(const float* __restrict__ mmf, int* __restrict__ lividx,
                       int* __restrict__ nliv) {
  int b = blockIdx.x, t = threadIdx.x;
  const float* mm = mmf + (size_t)b * NP;
  int* li = lividx + (size_t)b * NP;
  __shared__ int cnt[256];
  int loc[16];
  int c = 0;
#pragma unroll
  for (int i = 0; i < 16; ++i) {
    int lv = (mm[t * 16 + i] != 0.f) ? 1 : 0;
    loc[i] = lv;
    c += lv;
  }
  cnt[t] = c;
  __syncthreads();
  for (int s = 1; s < 256; s <<= 1) {
    int v = (t >= s) ? cnt[t - s] : 0;
    __syncthreads();
    cnt[t] += v;
    __syncthreads();
  }
  int base = cnt[t] - c;
#pragma unroll
  for (int i = 0; i < 16; ++i)
    if (loc[i]) li[base++] = t * 16 + i;
  int nl = cnt[255];
  if (t == 0) nliv[b] = nl;
  for (int i = nl + t; i < NP; i += 256) li[i] = 0;
}

// Bim[b][k=(c,di,dj)][xy] = fm zero-padded patch element
__global__ void k_im2col(const float* __restrict__ fm, float* __restrict__ Bim) {
  int idx = blockIdx.x * 256 + threadIdx.x;
  if (idx >= BSZ * KC * WH) return;
  int b = idx / (KC * WH);
  int rem = idx - b * (KC * WH);
  int k = rem >> 12, xy = rem & 4095;
  int c = k / 9, p = k - c * 9;
  int di = p / 3, dj = p - di * 3;
  int x = xy >> 6, y = xy & 63;
  int xi = x + di - 1, yj = y + dj - 1;
  float v = 0.f;
  if (xi >= 0 && xi < WD && yj >= 0 && yj < WD)
    v = fm[((size_t)(b * C + c)) * WH + xi * WD + yj];
  Bim[idx] = v;
}

// ---------------- tiled f32 GEMMs ----------------
#define BM 64
#define BN 64
#define BK 16
#define BN2 32

// cr[nc][xy] = sum_k Ak[liv[nc]][k] * Bim[k][xy]  -- compact rows only
__global__ __launch_bounds__(256) void k_gemm1(const float* __restrict__ A,
                                               const float* __restrict__ Bp,
                                               const int* __restrict__ liv,
                                               const int* __restrict__ nliv,
                                               float* __restrict__ Cp) {
  int nl = *nliv;
  int m0 = blockIdx.y * BM;
  if (m0 >= nl) return;
  int n0 = blockIdx.x * BN;
  __shared__ __align__(16) float As[BK][BM + 4];
  __shared__ __align__(16) float Bs[BK][BN + 4];
  int t = threadIdx.x;
  int tn = t & 15, tm = t >> 4;
  const float* Arow = A + (size_t)liv[m0 + (t >> 2)] * KC + ((t & 3) << 2);
  float acc[4][4] = {};
  for (int k0 = 0; k0 < KC; k0 += BK) {
    {
      int m = t >> 2, kq = (t & 3) << 2;
      const float4 v = *reinterpret_cast<const float4*>(Arow + k0);
      As[kq + 0][m] = v.x; As[kq + 1][m] = v.y; As[kq + 2][m] = v.z; As[kq + 3][m] = v.w;
    }
    {
      int r = t >> 4, c4 = (t & 15) << 2;
      *reinterpret_cast<float4*>(&Bs[r][c4]) =
          *reinterpret_cast<const float4*>(Bp + (size_t)(k0 + r) * WH + n0 + c4);
    }
    __syncthreads();
#pragma unroll
    for (int kk = 0; kk < BK; ++kk) {
      float4 a = *reinterpret_cast<const float4*>(&As[kk][tm * 4]);
      float4 bb = *reinterpret_cast<const float4*>(&Bs[kk][tn * 4]);
      float av[4] = {a.x, a.y, a.z, a.w};
      float bv[4] = {bb.x, bb.y, bb.z, bb.w};
#pragma unroll
      for (int i = 0; i < 4; ++i)
#pragma unroll
        for (int j = 0; j < 4; ++j) acc[i][j] += av[i] * bv[j];
    }
    __syncthreads();
  }
#pragma unroll
  for (int i = 0; i < 4; ++i) {
    float4 w = {acc[i][0], acc[i][1], acc[i][2], acc[i][3]};
    *reinterpret_cast<float4*>(Cp + (size_t)(m0 + tm * 4 + i) * WH + n0 + tn * 4) = w;
  }
}

// P[k2][xy] = sum_{nc<Kend} Ak[liv[nc]][k2] * att[nc][xy]
__global__ __launch_bounds__(256) void k_gemm2(const float* __restrict__ A,
                                               const float* __restrict__ att,
                                               const int* __restrict__ liv,
                                               const int* __restrict__ nliv,
                                               float* __restrict__ Cp) {
  int nl = *nliv;
  int Kend = (nl + BK - 1) & ~(BK - 1);
  int m0 = blockIdx.y * BM;   // over KC=576 -> 9 tiles
  int n0 = blockIdx.x * BN2;  // over WH -> 128 tiles
  __shared__ __align__(16) float As[BK][BM + 4];
  __shared__ __align__(16) float Bs[BK][BN2 + 4];
  int t = threadIdx.x;
  int tn = t & 15, tm = t >> 4;
  float acc[4][2] = {};
  for (int k0 = 0; k0 < Kend; k0 += BK) {
    {
      int r = t >> 4, c4 = (t & 15) << 2;
      int g = liv[k0 + r];
      const float4 v = *reinterpret_cast<const float4*>(A + (size_t)g * KC + m0 + c4);
      *reinterpret_cast<float4*>(&As[r][c4]) = v;
    }
    {
      int r = t >> 4, c2 = (t & 15) << 1;
      const float2 v = *reinterpret_cast<const float2*>(att + (size_t)(k0 + r) * WH + n0 + c2);
      Bs[r][c2] = v.x;
      Bs[r][c2 + 1] = v.y;
    }
    __syncthreads();
#pragma unroll
    for (int kk = 0; kk < BK; ++kk) {
      float4 a = *reinterpret_cast<const float4*>(&As[kk][tm * 4]);
      float av[4] = {a.x, a.y, a.z, a.w};
      float bv0 = Bs[kk][tn * 2], bv1 = Bs[kk][tn * 2 + 1];
#pragma unroll
      for (int i = 0; i < 4; ++i) {
        acc[i][0] += av[i] * bv0;
        acc[i][1] += av[i] * bv1;
      }
    }
    __syncthreads();
  }
#pragma unroll
  for (int i = 0; i < 4; ++i) {
    float2 w = {acc[i][0], acc[i][1]};
    *reinterpret_cast<float2*>(Cp + (size_t)(m0 + tm * 4 + i) * WH + n0 + tn * 2) = w;
  }
}

// ---------------- box filter (in-place, per-live-row LDS) ----------------
__global__ __launch_bounds__(256) void k_box(const int* __restrict__ nliv,
                                             float* __restrict__ cr) {
  if ((int)blockIdx.x >= *nliv) return;
  __shared__ __align__(16) float sIn[WH];
  __shared__ __align__(16) float sT[WH];
  float* row = cr + (size_t)blockIdx.x * WH;
  const float4* r4 = reinterpret_cast<const float4*>(row);
  float4* s4 = reinterpret_cast<float4*>(sIn);
  for (int i = threadIdx.x; i < WH / 4; i += 256) s4[i] = r4[i];
  __syncthreads();
  for (int i = threadIdx.x; i < WH; i += 256) {
    int y = i & 63;
    float v = sIn[i];
    if (y > 0) v += sIn[i - 1];
    if (y < 63) v += sIn[i + 1];
    sT[i] = v;
  }
  __syncthreads();
  for (int i = threadIdx.x; i < WH; i += 256) {
    int x = i >> 6;
    float v = sT[i];
    if (x > 0) v += sT[i - 64];
    if (x < 63) v += sT[i + 64];
    row[i] = v;
  }
}

// ------- column softmax, pass 1: per-thread-column online max/sum over a row segment
__global__ __launch_bounds__(256) void k_colstat(const float* __restrict__ cr,
                                                 const int* __restrict__ nliv,
                                                 float* __restrict__ pmax,
                                                 float* __restrict__ psum) {
  int xy = blockIdx.x * 256 + threadIdx.x;
  int nl = *nliv;
  int ns = (nl + 15) >> 4;  // rows per segment (16 segments)
  int r0 = blockIdx.y * ns;
  int r1 = min(r0 + ns, nl);
  float mx = -3.4e38f, s = 0.f;
  for (int r = r0; r < r1; ++r) {
    float v = cr[(size_t)r * WH + xy];
    if (v <= mx) {
      s += __expf(v - mx);
    } else {
      s = s * __expf(mx - v) + 1.f;
      mx = v;
    }
  }
  pmax[blockIdx.y * WH + xy] = mx;
  psum[blockIdx.y * WH + xy] = s;
}

// ------- column softmax, pass 2: merge 16 partials + dead-row term -> m2, inv
__global__ __launch_bounds__(256) void k_colmerge(const int* __restrict__ nliv,
                                                  const float* __restrict__ pmax,
                                                  const float* __restrict__ psum,
                                                  float* __restrict__ m2g,
                                                  float* __restrict__ invg) {
  int xy = blockIdx.x * 256 + threadIdx.x;
  int nl = *nliv;
  float M = -3.4e38f;
  for (int k = 0; k < 16; ++k) M = fmaxf(M, pmax[k * WH + xy]);
  float S = 0.f;
  if (M > -3.0e38f)
    for (int k = 0; k < 16; ++k) S += psum[k * WH + xy] * __expf(pmax[k * WH + xy] - M);
  int nm = NP - nl;
  float m2 = (nm > 0) ? fmaxf(M, 0.f) : M;
  float denom = (M > -3.0e38f ? S * __expf(M - m2) : 0.f) + (float)nm * __expf(-m2);
  m2g[xy] = m2;
  invg[xy] = 1.f / denom;
}

// ------- column softmax, pass 3: elementwise apply (in place); zero pad rows
__global__ __launch_bounds__(256) void k_apply(const int* __restrict__ nliv,
                                               const float* __restrict__ m2g,
                                               const float* __restrict__ invg,
                                               float* __restrict__ cr) {
  int i = blockIdx.x * 256 + threadIdx.x;  // float4 index
  int row = i >> 10;                        // WH/4 = 1024 float4 per row
  int nl = *nliv;
  int kend = (nl + 15) & ~15;
  if (row >= kend) return;
  float4* p = reinterpret_cast<float4*>(cr) + i;
  if (row >= nl) {
    *p = make_float4(0.f, 0.f, 0.f, 0.f);
    return;
  }
  int xy = (i & 1023) << 2;
  float4 v = *p;
  const float4 m2 = *reinterpret_cast<const float4*>(m2g + xy);
  const float4 iv = *reinterpret_cast<const float4*>(invg + xy);
  v.x = __expf(v.x - m2.x) * iv.x;
  v.y = __expf(v.y - m2.y) * iv.y;
  v.z = __expf(v.z - m2.z) * iv.z;
  v.w = __expf(v.w - m2.w) * iv.w;
  *p = v;
}

// rec[b][c][x][y] = sum_{i,j} P[b][(c,i,j)][x+1-i, y+1-j]
__global__ void k_rec(const float* __restrict__ P, float* __restrict__ out) {
  int idx = blockIdx.x * 256 + threadIdx.x;
  if (idx >= BSZ * C * WH) return;
  int b = idx >> 18;
  int r = idx & 262143;
  int c = r >> 12;
  int xy = r & 4095;
  int x = xy >> 6, y = xy & 63;
  const float* Pb = P + (size_t)b * KC * WH;
  float acc = 0.f;
#pragma unroll
  for (int i = 0; i < 3; ++i) {
    int xp = x + 1 - i;
    if (xp < 0 || xp >= WD) continue;
#pragma unroll
    for (int j = 0; j < 3; ++j) {
      int yp = y + 1 - j;
      if (yp < 0 || yp >= WD) continue;
      acc += Pb[(size_t)(c * 9 + i * 3 + j) * WH + xp * WD + yp];
    }
  }
  out[idx] = acc;
}

// ---------------- launcher ----------------

extern "C" void kernel_launch(void* const* d_in, const int* in_sizes, int n_in,
                              void* d_out, int out_size, void* d_ws, size_t ws_size,
                              hipStream_t stream) {
  const float* fg    = (const float*)d_in[0];
  const float* mask  = (const float*)d_in[1];
  // d_in[2] same_number_of_args unused; Wq_f/bq_f/Wk_f/bk_f (3..6) are dead inputs.
  const float* Wv_f  = (const float*)d_in[7];
  const float* bv_f  = (const float*)d_in[8];
  const float* Wq_p  = (const float*)d_in[9];
  const float* bq_p  = (const float*)d_in[10];
  const float* Wk_p  = (const float*)d_in[11];
  const float* bk_p  = (const float*)d_in[12];
  const float* Wv_p  = (const float*)d_in[13];
  const float* bv_p  = (const float*)d_in[14];
  const float* gamma = (const float*)d_in[15];

  float* ws = (float*)d_ws;
  size_t off = 0;
  auto alloc = [&](size_t n) { size_t o = off; off += (n + 63) & ~(size_t)63; return o; };
  float* Ak   = ws + alloc((size_t)BSZ * NP * KC);   //  4,718,592
  float* Bim  = ws + alloc((size_t)BSZ * KC * WH);   //  4,718,592 (Pb aliases later)
  float* mmf  = ws + alloc((size_t)BSZ * NP);
  float* mu   = ws + alloc(BSZ * C);
  float* vmn  = ws + alloc(BSZ * C);
  float* u    = ws + alloc(C);
  float* bks  = ws + alloc(64);
  int*   lividx = (int*)(ws + alloc((size_t)BSZ * NP));
  int*   nliv   = (int*)(ws + alloc(64));
  float* pmax = ws + alloc((size_t)16 * WH);
  float* psum = ws + alloc((size_t)16 * WH);
  float* m2g  = ws + alloc(WH);
  float* invg = ws + alloc(WH);
  float* cr   = ws + alloc((size_t)NP * WH);         // 16,777,216 (single sample)
  // prep fields alias the head of cr (all dead before k_gemm1 writes cr):
  size_t poff = 0;
  auto palloc = [&](size_t n) { size_t o = poff; poff += (n + 63) & ~(size_t)63; return o; };
  float* bgp = cr + palloc((size_t)BSZ * PP * C);
  float* Vg  = cr + palloc((size_t)BSZ * PP * C);
  float* Sg  = cr + palloc((size_t)BSZ * PP);
  float* fmb = cr + palloc((size_t)BSZ * C * WH);
  float* Pb  = Bim;  // gemm2 output aliases Bim (dead after that sample's gemm1)
  (void)ws_size; (void)in_sizes; (void)n_in; (void)out_size;

  k_prep<<<1, 64, 0, stream>>>(Wk_p, bk_p, u, bks);
  k_mu<<<BSZ * C, 256, 0, stream>>>(fg, mask, mu);
  k_vmean<<<1, 128, 0, stream>>>(Wv_f, bv_f, mu, vmn);
  k_fm<<<(BSZ * C * WH + 255) / 256, 256, 0, stream>>>(fg, mask, vmn, fmb);
  k_bgpT<<<dim3(PW, BSZ), 256, 0, stream>>>(fg, mask, bgp);
  k_vgT<<<(BSZ * PP + 3) / 4, 256, 0, stream>>>(bgp, Wv_p, bv_p, Vg);
  k_sgT<<<(BSZ * PP + 3) / 4, 256, 0, stream>>>(bgp, u, bks, Sg);
  k_gap<<<BSZ * NP, 64, 0, stream>>>(bgp, mask, Sg, Vg, Wq_p, bq_p, gamma, Ak, mmf);
  k_scan<<<BSZ, 256, 0, stream>>>(mmf, lividx, nliv);
  k_im2col<<<(BSZ * KC * WH + 255) / 256, 256, 0, stream>>>(fmb, Bim);
  for (int b = 0; b < BSZ; ++b) {
    const float* Akb = Ak + (size_t)b * NP * KC;
    const int* livb = lividx + (size_t)b * NP;
    const int* nlb = nliv + b;
    k_gemm1<<<dim3(WH / BN, NP / BM), 256, 0, stream>>>(Akb, Bim + (size_t)b * KC * WH,
                                                        livb, nlb, cr);
    k_box<<<NP, 256, 0, stream>>>(nlb, cr);
    k_colstat<<<dim3(WH / 256, 16), 256, 0, stream>>>(cr, nlb, pmax, psum);
    k_colmerge<<<WH / 256, 256, 0, stream>>>(nlb, pmax, psum, m2g, invg);
    k_apply<<<NP * (WH / 4) / 256, 256, 0, stream>>>(nlb, m2g, invg, cr);
    k_gemm2<<<dim3(WH / BN2, KC / BM), 256, 0, stream>>>(Akb, cr, livb, nlb,
                                                         Pb + (size_t)b * KC * WH);
  }
  k_rec<<<(BSZ * C * WH + 255) / 256, 256, 0, stream>>>(Pb, (float*)d_out);
}

// Round 8
// 825.955 us; speedup vs baseline: 2.6062x; 1.6167x over previous
//
#include <hip/hip_runtime.h>

// GLA forward. Structure:
//  - MPGA collapses: fm = mask ? fg : (Wv_f @ mean(bg) + bv_f)
//  - live patches (3x3 mask window == 0): GAP energy is exactly uniform ->
//    ck = (gamma/9) * Vg window, L2-normalized. Dead patches never consumed.
//  - compaction: only nlive rows flow through gemm1/box/softmax/gemm2.
//  - GEMMs: split-bf16 MFMA (hi/lo, 3 products) on v_mfma_f32_16x16x32_bf16.

#define BSZ 2
#define C 64
#define WD 64
#define WH 4096
#define PW 66
#define PP 4356
#define KC 576
#define NP 4096

typedef unsigned short u16;
typedef short bf16x8 __attribute__((ext_vector_type(8)));
typedef float f32x4 __attribute__((ext_vector_type(4)));

__device__ inline u16 bf16_rne(float x) {
  unsigned u = __float_as_uint(x);
  return (u16)((u + 0x7FFFu + ((u >> 16) & 1u)) >> 16);
}
__device__ inline float bf16_tof(u16 h) { return __uint_as_float(((unsigned)h) << 16); }
__device__ inline void split2(float x, u16& h, u16& l) {
  h = bf16_rne(x);
  l = bf16_rne(x - bf16_tof(h));
}

// ---------------- prep ----------------

__global__ void k_mu(const float* __restrict__ fg, const float* __restrict__ mask,
                     float* __restrict__ mu) {
  int bc = blockIdx.x;
  int b = bc >> 6;
  const float* f = fg + (size_t)bc * WH;
  const float* mk = mask + (size_t)b * WH;
  float sum = 0.f;
  for (int i = threadIdx.x; i < WH; i += 256) sum += f[i] * (1.f - mk[i]);
  __shared__ float red[256];
  red[threadIdx.x] = sum;
  __syncthreads();
  for (int s = 128; s > 0; s >>= 1) {
    if (threadIdx.x < s) red[threadIdx.x] += red[threadIdx.x + s];
    __syncthreads();
  }
  if (threadIdx.x == 0) mu[bc] = red[0] / (float)WH;
}

__global__ void k_vmean(const float* __restrict__ Wv_f, const float* __restrict__ bv_f,
                        const float* __restrict__ mu, float* __restrict__ vmean) {
  int t = threadIdx.x;
  int b = t >> 6, c = t & 63;
  float acc = bv_f[c];
  for (int cc = 0; cc < C; ++cc) acc += Wv_f[c * C + cc] * mu[b * C + cc];
  vmean[t] = acc;
}

__global__ void k_fm(const float* __restrict__ fg, const float* __restrict__ mask,
                     const float* __restrict__ vmean, float* __restrict__ fm) {
  int idx = blockIdx.x * 256 + threadIdx.x;
  if (idx >= BSZ * C * WH) return;
  int b = idx >> 18;
  int c = (idx >> 12) & 63;
  int pos = idx & (WH - 1);
  float m = mask[b * WH + pos];
  fm[idx] = fg[idx] * m + (1.f - m) * vmean[b * C + c];
}

// bgp[b][pos][c] = padded background + 1e-7
__global__ void k_bgpT(const float* __restrict__ fg, const float* __restrict__ mask,
                       float* __restrict__ bgp) {
  int b = blockIdx.y, xp = blockIdx.x;
  float* out = bgp + ((size_t)b * PP + (size_t)xp * PW) * C;
  int t = threadIdx.x;
  __shared__ float tile[64][65];
  int xi = xp - 1;
  if (xi >= 0 && xi < WD) {
    const float* fgb = fg + (size_t)b * C * WH + (size_t)xi * WD;
    const float* mkb = mask + (size_t)b * WH + (size_t)xi * WD;
    for (int i = t; i < 64 * 64; i += 256) {
      int c = i >> 6, y = i & 63;
      tile[c][y] = fgb[(size_t)c * WH + y] * (1.f - mkb[y]);
    }
  }
  __syncthreads();
  for (int i = t; i < PW * C; i += 256) {
    int yp = i >> 6, c = i & 63;
    float v = 1e-7f;
    int yj = yp - 1;
    if (xi >= 0 && xi < WD && yj >= 0 && yj < WD) v += tile[c][yj];
    out[(size_t)yp * C + c] = v;
  }
}

// Vg[b][pos][o] = Wv_p @ bgp[pos,:] + bv_p
__global__ void k_vgT(const float* __restrict__ bgp, const float* __restrict__ Wv_p,
                      const float* __restrict__ bv_p, float* __restrict__ Vg) {
  __shared__ float Wt[64][65];
  __shared__ float bgl[4][64];
  int t = threadIdx.x;
  for (int i = t; i < 4096; i += 256) Wt[i & 63][i >> 6] = Wv_p[i];
  int pos0 = blockIdx.x * 4;
  {
    int p2 = t >> 6, c = t & 63;
    int gp = pos0 + p2;
    bgl[p2][c] = (gp < BSZ * PP) ? bgp[(size_t)gp * C + c] : 0.f;
  }
  __syncthreads();
  int pi = t >> 6, o = t & 63;
  int gpos = pos0 + pi;
  if (gpos < BSZ * PP) {
    float acc = bv_p[o];
    for (int c = 0; c < 64; ++c) acc += Wt[c][o] * bgl[pi][c];
    Vg[(size_t)gpos * C + o] = acc;
  }
}

// mmf[b][n] = 1 if 3x3 mask window all zero
__global__ void k_mmf(const float* __restrict__ mask, float* __restrict__ mmf) {
  int idx = blockIdx.x * 256 + threadIdx.x;
  if (idx >= BSZ * NP) return;
  int b = idx >> 12, n = idx & 4095;
  int x = n >> 6, y = n & 63;
  float z = 0.f;
  for (int di = -1; di <= 1; ++di)
    for (int dj = -1; dj <= 1; ++dj) {
      int xi = x + di, yj = y + dj;
      if (xi >= 0 && xi < WD && yj >= 0 && yj < WD) z += mask[b * WH + xi * WD + yj];
    }
  mmf[idx] = (z == 0.f) ? 1.f : 0.f;
}

__global__ void k_scan(const float* __restrict__ mmf, int* __restrict__ lividx,
                       int* __restrict__ nliv) {
  int b = blockIdx.x, t = threadIdx.x;
  const float* mm = mmf + (size_t)b * NP;
  int* li = lividx + (size_t)b * NP;
  __shared__ int cnt[256];
  int loc[16];
  int c = 0;
#pragma unroll
  for (int i = 0; i < 16; ++i) {
    int lv = (mm[t * 16 + i] != 0.f) ? 1 : 0;
    loc[i] = lv;
    c += lv;
  }
  cnt[t] = c;
  __syncthreads();
  for (int s = 1; s < 256; s <<= 1) {
    int v = (t >= s) ? cnt[t - s] : 0;
    __syncthreads();
    cnt[t] += v;
    __syncthreads();
  }
  int base = cnt[t] - c;
#pragma unroll
  for (int i = 0; i < 16; ++i)
    if (loc[i]) li[base++] = t * 16 + i;
  int nl = cnt[255];
  if (t == 0) nliv[b] = nl;
  for (int i = nl + t; i < NP; i += 256) li[i] = 0;
}

// live-patch ck: (gamma/9)*Vg window, L2-normalized -> Akc hi/lo [nc][KC]
__global__ void k_ck(const float* __restrict__ Vg, const int* __restrict__ lividx,
                     const int* __restrict__ nliv, const float* __restrict__ gamma,
                     u16* __restrict__ AkcH, u16* __restrict__ AkcL) {
  int b = blockIdx.y, nc = blockIdx.x;
  if (nc >= nliv[b]) return;
  int n = lividx[(size_t)b * NP + nc];
  int x = n >> 6, y = n & 63;
  int c = threadIdx.x;
  const float* vg = Vg + (size_t)b * PP * C;
  float g9 = gamma[0] * (1.f / 9.f);
  float o[9];
  float ss = 0.f;
#pragma unroll
  for (int p = 0; p < 9; ++p) {
    int di = p / 3, dj = p % 3;
    float v = g9 * vg[(size_t)((x + di) * PW + (y + dj)) * C + c];
    o[p] = v;
    ss += v * v;
  }
#pragma unroll
  for (int off = 32; off > 0; off >>= 1) ss += __shfl_down(ss, off, 64);
  ss = __shfl(ss, 0, 64);
  float rn = 1.f / sqrtf(ss);
  u16* ph = AkcH + ((size_t)b * NP + nc) * KC + c * 9;
  u16* pl = AkcL + ((size_t)b * NP + nc) * KC + c * 9;
#pragma unroll
  for (int p = 0; p < 9; ++p) {
    u16 h, l;
    split2(o[p] * rn, h, l);
    ph[p] = h;
    pl[p] = l;
  }
}

// Akc [NP][KC] -> AkT [KC][NP] (hi/lo)
__global__ void k_trA(const u16* __restrict__ Sh, const u16* __restrict__ Sl,
                      u16* __restrict__ Dh, u16* __restrict__ Dl) {
  __shared__ __align__(16) u16 tile[64][72];
  int x0 = blockIdx.x * 64, k0 = blockIdx.y * 64;
  int t = threadIdx.x;
  for (int pass = 0; pass < 2; ++pass) {
    const u16* S = pass ? Sl : Sh;
    u16* D = pass ? Dl : Dh;
    for (int ch = t; ch < 512; ch += 256) {
      int r = ch >> 3, c0 = (ch & 7) * 8;
      *reinterpret_cast<uint4*>(&tile[r][c0]) =
          *reinterpret_cast<const uint4*>(S + (size_t)(x0 + r) * KC + k0 + c0);
    }
    __syncthreads();
    for (int ch = t; ch < 512; ch += 256) {
      int kr = ch >> 3, c0 = (ch & 7) * 8;
      union { u16 u[8]; uint4 v; } pk;
#pragma unroll
      for (int j = 0; j < 8; ++j) pk.u[j] = tile[c0 + j][kr];
      *reinterpret_cast<uint4*>(D + (size_t)(k0 + kr) * NP + x0 + c0) = pk.v;
    }
    __syncthreads();
  }
}

// im2col directly transposed + split: BimT hi/lo [xy][KC]
__global__ void k_im2colT(const float* __restrict__ fm, u16* __restrict__ base) {
  int ch = blockIdx.x * 256 + threadIdx.x;
  if (ch >= BSZ * WH * 72) return;
  int b = ch / (WH * 72);
  int rem = ch - b * WH * 72;
  int xy = rem / 72, kp = rem - xy * 72;
  int x = xy >> 6, y = xy & 63;
  union { u16 u[8]; uint4 v; } H, L;
#pragma unroll
  for (int j = 0; j < 8; ++j) {
    int k = kp * 8 + j;
    int c = k / 9, p = k - c * 9;
    int xi = x + p / 3 - 1, yj = y + p % 3 - 1;
    float v = 0.f;
    if (xi >= 0 && xi < WD && yj >= 0 && yj < WD)
      v = fm[((size_t)(b * C + c)) * WH + (xi << 6) + yj];
    split2(v, H.u[j], L.u[j]);
  }
  u16* bh = base + (size_t)b * 2 * WH * KC;
  u16* bl = bh + (size_t)WH * KC;
  *reinterpret_cast<uint4*>(bh + (size_t)xy * KC + kp * 8) = H.v;
  *reinterpret_cast<uint4*>(bl + (size_t)xy * KC + kp * 8) = L.v;
}

// ---------------- MFMA GEMMs ----------------

// gemm1: cr[m][n] = Akc[m][:] . BimT[n][:]   M-tile 128, N-tile 64, K=576
__global__ __launch_bounds__(256, 4) void k_gemmA(
    const u16* __restrict__ Ah, const u16* __restrict__ Al,
    const u16* __restrict__ Bh, const u16* __restrict__ Bl,
    const int* __restrict__ nliv, float* __restrict__ Cp) {
  int nl = *nliv;
  int m0 = blockIdx.y * 128;
  if (m0 >= nl) return;
  int n0 = blockIdx.x * 64;
  __shared__ __align__(16) u16 As[2][128][40];
  __shared__ __align__(16) u16 Bs[2][64][40];
  int t = threadIdx.x;
  f32x4 zero = {0.f, 0.f, 0.f, 0.f};
  f32x4 acc[2][4];
#pragma unroll
  for (int r = 0; r < 2; ++r)
#pragma unroll
    for (int c = 0; c < 4; ++c) acc[r][c] = zero;
  int l = t & 63, w = t >> 6;
  int lr = l & 15, lk = (l >> 4) * 8;
  for (int k0 = 0; k0 < KC; k0 += 32) {
    __syncthreads();
    for (int ch = t; ch < 1536; ch += 256) {
      const u16* src;
      u16* dst;
      if (ch < 1024) {
        int hl = ch >> 9, r = (ch >> 2) & 127, p = ch & 3;
        src = (hl ? Al : Ah) + (size_t)(m0 + r) * KC + k0 + p * 8;
        dst = &As[hl][r][p * 8];
      } else {
        int c2 = ch - 1024;
        int hl = c2 >> 8, r = (c2 >> 2) & 63, p = c2 & 3;
        src = (hl ? Bl : Bh) + (size_t)(n0 + r) * KC + k0 + p * 8;
        dst = &Bs[hl][r][p * 8];
      }
      *reinterpret_cast<uint4*>(dst) = *reinterpret_cast<const uint4*>(src);
    }
    __syncthreads();
    bf16x8 ah[2], al2[2], bh[4], bl2[4];
#pragma unroll
    for (int r = 0; r < 2; ++r) {
      ah[r] = *reinterpret_cast<const bf16x8*>(&As[0][32 * w + 16 * r + lr][lk]);
      al2[r] = *reinterpret_cast<const bf16x8*>(&As[1][32 * w + 16 * r + lr][lk]);
    }
#pragma unroll
    for (int c = 0; c < 4; ++c) {
      bh[c] = *reinterpret_cast<const bf16x8*>(&Bs[0][16 * c + lr][lk]);
      bl2[c] = *reinterpret_cast<const bf16x8*>(&Bs[1][16 * c + lr][lk]);
    }
#pragma unroll
    for (int r = 0; r < 2; ++r)
#pragma unroll
      for (int c = 0; c < 4; ++c) {
        acc[r][c] = __builtin_amdgcn_mfma_f32_16x16x32_bf16(ah[r], bh[c], acc[r][c], 0, 0, 0);
        acc[r][c] = __builtin_amdgcn_mfma_f32_16x16x32_bf16(ah[r], bl2[c], acc[r][c], 0, 0, 0);
        acc[r][c] = __builtin_amdgcn_mfma_f32_16x16x32_bf16(al2[r], bh[c], acc[r][c], 0, 0, 0);
      }
  }
#pragma unroll
  for (int r = 0; r < 2; ++r)
#pragma unroll
    for (int c = 0; c < 4; ++c)
#pragma unroll
      for (int q = 0; q < 4; ++q) {
        int row = m0 + 32 * w + 16 * r + ((l >> 4) << 2) + q;
        Cp[(size_t)row * WH + n0 + 16 * c + lr] = acc[r][c][q];
      }
}

// gemm2: P[m][n] = sum_k AkT[m][k] * att[k][n]  M-tile 64 (9 tiles), K dynamic
__global__ __launch_bounds__(256, 4) void k_gemmB(
    const u16* __restrict__ Ah, const u16* __restrict__ Al,
    const float* __restrict__ Bsrc, const int* __restrict__ nliv,
    float* __restrict__ Cp) {
  int nl = *nliv;
  int Kend = (nl + 31) & ~31;
  int m0 = blockIdx.y * 64;
  int n0 = blockIdx.x * 64;
  __shared__ __align__(16) u16 As[2][64][40];
  __shared__ __align__(16) u16 Bs[2][64][40];
  __shared__ __align__(16) float Bf[32][68];
  int t = threadIdx.x;
  f32x4 zero = {0.f, 0.f, 0.f, 0.f};
  f32x4 acc[4];
#pragma unroll
  for (int c = 0; c < 4; ++c) acc[c] = zero;
  int l = t & 63, w = t >> 6;
  int lr = l & 15, lk = (l >> 4) * 8;
  for (int k0 = 0; k0 < Kend; k0 += 32) {
    __syncthreads();
    for (int ch = t; ch < 512; ch += 256) {
      int hl = ch >> 8, r = (ch >> 2) & 63, p = ch & 3;
      const u16* src = (hl ? Al : Ah) + (size_t)(m0 + r) * NP + k0 + p * 8;
      *reinterpret_cast<uint4*>(&As[hl][r][p * 8]) = *reinterpret_cast<const uint4*>(src);
    }
    {
      int r = t >> 3, c0 = (t & 7) * 8;
      int krow = k0 + r;
      float4 v0 = {0.f, 0.f, 0.f, 0.f}, v1 = {0.f, 0.f, 0.f, 0.f};
      if (krow < nl) {
        const float* bp = Bsrc + (size_t)krow * WH + n0 + c0;
        v0 = *reinterpret_cast<const float4*>(bp);
        v1 = *reinterpret_cast<const float4*>(bp + 4);
      }
      *reinterpret_cast<float4*>(&Bf[r][c0]) = v0;
      *reinterpret_cast<float4*>(&Bf[r][c0 + 4]) = v1;
    }
    __syncthreads();
    {
      int n = t >> 2, kq = (t & 3) * 8;
      union { u16 u[8]; uint4 v; } H, L;
#pragma unroll
      for (int j = 0; j < 8; ++j) {
        float v = Bf[kq + j][n];
        split2(v, H.u[j], L.u[j]);
      }
      *reinterpret_cast<uint4*>(&Bs[0][n][kq]) = H.v;
      *reinterpret_cast<uint4*>(&Bs[1][n][kq]) = L.v;
    }
    __syncthreads();
    bf16x8 ah, al2, bh[4], bl2[4];
    ah = *reinterpret_cast<const bf16x8*>(&As[0][16 * w + lr][lk]);
    al2 = *reinterpret_cast<const bf16x8*>(&As[1][16 * w + lr][lk]);
#pragma unroll
    for (int c = 0; c < 4; ++c) {
      bh[c] = *reinterpret_cast<const bf16x8*>(&Bs[0][16 * c + lr][lk]);
      bl2[c] = *reinterpret_cast<const bf16x8*>(&Bs[1][16 * c + lr][lk]);
    }
#pragma unroll
    for (int c = 0; c < 4; ++c) {
      acc[c] = __builtin_amdgcn_mfma_f32_16x16x32_bf16(ah, bh[c], acc[c], 0, 0, 0);
      acc[c] = __builtin_amdgcn_mfma_f32_16x16x32_bf16(ah, bl2[c], acc[c], 0, 0, 0);
      acc[c] = __builtin_amdgcn_mfma_f32_16x16x32_bf16(al2, bh[c], acc[c], 0, 0, 0);
    }
  }
#pragma unroll
  for (int c = 0; c < 4; ++c)
#pragma unroll
    for (int q = 0; q < 4; ++q) {
      int row = m0 + 16 * w + ((l >> 4) << 2) + q;
      Cp[(size_t)row * WH + n0 + 16 * c + lr] = acc[c][q];
    }
}

// ---------------- box / softmax / rec ----------------

__global__ __launch_bounds__(256) void k_box(const int* __restrict__ nliv,
                                             float* __restrict__ cr) {
  if ((int)blockIdx.x >= *nliv) return;
  __shared__ __align__(16) float sIn[WH];
  __shared__ __align__(16) float sT[WH];
  float* row = cr + (size_t)blockIdx.x * WH;
  const float4* r4 = reinterpret_cast<const float4*>(row);
  float4* s4 = reinterpret_cast<float4*>(sIn);
  for (int i = threadIdx.x; i < WH / 4; i += 256) s4[i] = r4[i];
  __syncthreads();
  for (int i = threadIdx.x; i < WH; i += 256) {
    int y = i & 63;
    float v = sIn[i];
    if (y > 0) v += sIn[i - 1];
    if (y < 63) v += sIn[i + 1];
    sT[i] = v;
  }
  __syncthreads();
  for (int i = threadIdx.x; i < WH; i += 256) {
    int x = i >> 6;
    float v = sT[i];
    if (x > 0) v += sT[i - 64];
    if (x < 63) v += sT[i + 64];
    row[i] = v;
  }
}

__global__ __launch_bounds__(256) void k_colstat(const float* __restrict__ cr,
                                                 const int* __restrict__ nliv,
                                                 float* __restrict__ pmax,
                                                 float* __restrict__ psum) {
  int xy = blockIdx.x * 256 + threadIdx.x;
  int nl = *nliv;
  int ns = (nl + 15) >> 4;
  int r0 = blockIdx.y * ns;
  int r1 = min(r0 + ns, nl);
  float mx = -3.4e38f, s = 0.f;
  for (int r = r0; r < r1; ++r) {
    float v = cr[(size_t)r * WH + xy];
    if (v <= mx) {
      s += __expf(v - mx);
    } else {
      s = s * __expf(mx - v) + 1.f;
      mx = v;
    }
  }
  pmax[blockIdx.y * WH + xy] = mx;
  psum[blockIdx.y * WH + xy] = s;
}

__global__ __launch_bounds__(256) void k_colmerge(const int* __restrict__ nliv,
                                                  const float* __restrict__ pmax,
                                                  const float* __restrict__ psum,
                                                  float* __restrict__ m2g,
                                                  float* __restrict__ invg) {
  int xy = blockIdx.x * 256 + threadIdx.x;
  int nl = *nliv;
  float M = -3.4e38f;
  for (int k = 0; k < 16; ++k) M = fmaxf(M, pmax[k * WH + xy]);
  float S = 0.f;
  if (M > -3.0e38f)
    for (int k = 0; k < 16; ++k) S += psum[k * WH + xy] * __expf(pmax[k * WH + xy] - M);
  int nm = NP - nl;
  float m2 = (nm > 0) ? fmaxf(M, 0.f) : M;
  float denom = (M > -3.0e38f ? S * __expf(M - m2) : 0.f) + (float)nm * __expf(-m2);
  m2g[xy] = m2;
  invg[xy] = 1.f / denom;
}

__global__ __launch_bounds__(256) void k_apply(const int* __restrict__ nliv,
                                               const float* __restrict__ m2g,
                                               const float* __restrict__ invg,
                                               float* __restrict__ cr) {
  int i = blockIdx.x * 256 + threadIdx.x;
  int row = i >> 10;
  int nl = *nliv;
  int kend = (nl + 31) & ~31;
  if (row >= kend) return;
  float4* p = reinterpret_cast<float4*>(cr) + i;
  if (row >= nl) {
    *p = make_float4(0.f, 0.f, 0.f, 0.f);
    return;
  }
  int xy = (i & 1023) << 2;
  float4 v = *p;
  const float4 m2 = *reinterpret_cast<const float4*>(m2g + xy);
  const float4 iv = *reinterpret_cast<const float4*>(invg + xy);
  v.x = __expf(v.x - m2.x) * iv.x;
  v.y = __expf(v.y - m2.y) * iv.y;
  v.z = __expf(v.z - m2.z) * iv.z;
  v.w = __expf(v.w - m2.w) * iv.w;
  *p = v;
}

__global__ void k_rec(const float* __restrict__ P, float* __restrict__ out) {
  int idx = blockIdx.x * 256 + threadIdx.x;
  if (idx >= BSZ * C * WH) return;
  int b = idx >> 18;
  int r = idx & 262143;
  int c = r >> 12;
  int xy = r & 4095;
  int x = xy >> 6, y = xy & 63;
  const float* Pb = P + (size_t)b * KC * WH;
  float acc = 0.f;
#pragma unroll
  for (int i = 0; i < 3; ++i) {
    int xp = x + 1 - i;
    if (xp < 0 || xp >= WD) continue;
#pragma unroll
    for (int j = 0; j < 3; ++j) {
      int yp = y + 1 - j;
      if (yp < 0 || yp >= WD) continue;
      acc += Pb[(size_t)(c * 9 + i * 3 + j) * WH + xp * WD + yp];
    }
  }
  out[idx] = acc;
}

// ---------------- launcher ----------------

extern "C" void kernel_launch(void* const* d_in, const int* in_sizes, int n_in,
                              void* d_out, int out_size, void* d_ws, size_t ws_size,
                              hipStream_t stream) {
  const float* fg    = (const float*)d_in[0];
  const float* mask  = (const float*)d_in[1];
  const float* Wv_f  = (const float*)d_in[7];
  const float* bv_f  = (const float*)d_in[8];
  const float* Wv_p  = (const float*)d_in[13];
  const float* bv_p  = (const float*)d_in[14];
  const float* gamma = (const float*)d_in[15];

  float* ws = (float*)d_ws;
  size_t off = 0;
  auto alloc = [&](size_t n) { size_t o = off; off += (n + 63) & ~(size_t)63; return o; };
  // bf16 regions (sizes in float units; 2 shorts per float)
  u16* AkcH = (u16*)(ws + alloc((size_t)BSZ * NP * KC / 2));
  u16* AkcL = (u16*)(ws + alloc((size_t)BSZ * NP * KC / 2));
  u16* AkTH = (u16*)(ws + alloc((size_t)KC * NP / 2));
  u16* AkTL = (u16*)(ws + alloc((size_t)KC * NP / 2));
  float* BimTPb = ws + alloc((size_t)BSZ * KC * WH);  // per-sample: [hi|lo] shorts == Pb f32
  float* mmf  = ws + alloc((size_t)BSZ * NP);
  int* lividx = (int*)(ws + alloc((size_t)BSZ * NP));
  int* nliv   = (int*)(ws + alloc(64));
  float* mu   = ws + alloc(BSZ * C);
  float* vmn  = ws + alloc(BSZ * C);
  float* pmax = ws + alloc((size_t)16 * WH);
  float* psum = ws + alloc((size_t)16 * WH);
  float* m2g  = ws + alloc(WH);
  float* invg = ws + alloc(WH);
  float* cr   = ws + alloc((size_t)NP * WH);  // single sample
  // prep fields alias head of cr (dead before gemmA writes cr)
  size_t poff = 0;
  auto palloc = [&](size_t n) { size_t o = poff; poff += (n + 63) & ~(size_t)63; return o; };
  float* bgp = cr + palloc((size_t)BSZ * PP * C);
  float* Vg  = cr + palloc((size_t)BSZ * PP * C);
  float* fmb = cr + palloc((size_t)BSZ * C * WH);
  (void)ws_size; (void)in_sizes; (void)n_in; (void)out_size;

  k_mu<<<BSZ * C, 256, 0, stream>>>(fg, mask, mu);
  k_vmean<<<1, 128, 0, stream>>>(Wv_f, bv_f, mu, vmn);
  k_fm<<<(BSZ * C * WH + 255) / 256, 256, 0, stream>>>(fg, mask, vmn, fmb);
  k_bgpT<<<dim3(PW, BSZ), 256, 0, stream>>>(fg, mask, bgp);
  k_vgT<<<(BSZ * PP + 3) / 4, 256, 0, stream>>>(bgp, Wv_p, bv_p, Vg);
  k_mmf<<<(BSZ * NP + 255) / 256, 256, 0, stream>>>(mask, mmf);
  k_scan<<<BSZ, 256, 0, stream>>>(mmf, lividx, nliv);
  k_ck<<<dim3(NP, BSZ), 64, 0, stream>>>(Vg, lividx, nliv, gamma, AkcH, AkcL);
  k_im2colT<<<(BSZ * WH * 72 + 255) / 256, 256, 0, stream>>>(fmb, (u16*)BimTPb);

  for (int b = 0; b < BSZ; ++b) {
    const u16* AkcHb = AkcH + (size_t)b * NP * KC;
    const u16* AkcLb = AkcL + (size_t)b * NP * KC;
    const u16* BimTh = (const u16*)BimTPb + (size_t)b * 2 * WH * KC;
    const u16* BimTl = BimTh + (size_t)WH * KC;
    float* Pb = BimTPb + (size_t)b * KC * WH;
    const int* nlb = nliv + b;
    k_trA<<<dim3(NP / 64, KC / 64), 256, 0, stream>>>(AkcHb, AkcLb, AkTH, AkTL);
    k_gemmA<<<dim3(WH / 64, NP / 128), 256, 0, stream>>>(AkcHb, AkcLb, BimTh, BimTl,
                                                         nlb, cr);
    k_box<<<NP, 256, 0, stream>>>(nlb, cr);
    k_colstat<<<dim3(WH / 256, 16), 256, 0, stream>>>(cr, nlb, pmax, psum);
    k_colmerge<<<WH / 256, 256, 0, stream>>>(nlb, pmax, psum, m2g, invg);
    k_apply<<<NP * (WH / 4) / 256, 256, 0, stream>>>(nlb, m2g, invg, cr);
    k_gemmB<<<dim3(WH / 64, KC / 64), 256, 0, stream>>>(AkTH, AkTL, cr, nlb, Pb);
  }
  k_rec<<<(BSZ * C * WH + 255) / 256, 256, 0, stream>>>(BimTPb, (float*)d_out);
}

// Round 10
// 793.080 us; speedup vs baseline: 2.7143x; 1.0415x over previous
//
#include <hip/hip_runtime.h>

// GLA forward. Structure:
//  - MPGA collapses: fm = mask ? fg : (Wv_f @ mean(bg) + bv_f)
//  - live patches (3x3 mask window == 0): GAP energy is exactly uniform ->
//    ck = (gamma/9) * Vg window, L2-normalized. Dead patches never consumed.
//  - compaction: only nlive rows flow through gemm1/box/softmax/gemm2.
//  - GEMMs: split-bf16 MFMA (hi/lo, 3 products) on v_mfma_f32_16x16x32_bf16.
//  - att is packed (bf16hi<<16)|bf16lo in place of cr by k_apply; gemmB
//    unpacks with shifts (split done once globally, not 9x per m-tile).

#define BSZ 2
#define C 64
#define WD 64
#define WH 4096
#define PW 66
#define PP 4356
#define KC 576
#define NP 4096

typedef unsigned short u16;
typedef unsigned int u32;
typedef short bf16x8 __attribute__((ext_vector_type(8)));
typedef float f32x4 __attribute__((ext_vector_type(4)));

__device__ inline u16 bf16_rne(float x) {
  unsigned u = __float_as_uint(x);
  return (u16)((u + 0x7FFFu + ((u >> 16) & 1u)) >> 16);
}
__device__ inline float bf16_tof(u16 h) { return __uint_as_float(((unsigned)h) << 16); }
__device__ inline void split2(float x, u16& h, u16& l) {
  h = bf16_rne(x);
  l = bf16_rne(x - bf16_tof(h));
}
__device__ inline u32 pack2(float x) {
  u16 h, l;
  split2(x, h, l);
  return ((u32)h << 16) | (u32)l;
}

// ---------------- prep ----------------

__global__ void k_mu(const float* __restrict__ fg, const float* __restrict__ mask,
                     float* __restrict__ mu) {
  int bc = blockIdx.x;
  int b = bc >> 6;
  const float* f = fg + (size_t)bc * WH;
  const float* mk = mask + (size_t)b * WH;
  float sum = 0.f;
  for (int i = threadIdx.x; i < WH; i += 256) sum += f[i] * (1.f - mk[i]);
  __shared__ float red[256];
  red[threadIdx.x] = sum;
  __syncthreads();
  for (int s = 128; s > 0; s >>= 1) {
    if (threadIdx.x < s) red[threadIdx.x] += red[threadIdx.x + s];
    __syncthreads();
  }
  if (threadIdx.x == 0) mu[bc] = red[0] / (float)WH;
}

__global__ void k_vmean(const float* __restrict__ Wv_f, const float* __restrict__ bv_f,
                        const float* __restrict__ mu, float* __restrict__ vmean) {
  int t = threadIdx.x;
  int b = t >> 6, c = t & 63;
  float acc = bv_f[c];
  for (int cc = 0; cc < C; ++cc) acc += Wv_f[c * C + cc] * mu[b * C + cc];
  vmean[t] = acc;
}

__global__ void k_fm(const float* __restrict__ fg, const float* __restrict__ mask,
                     const float* __restrict__ vmean, float* __restrict__ fm) {
  int idx = blockIdx.x * 256 + threadIdx.x;
  if (idx >= BSZ * C * WH) return;
  int b = idx >> 18;
  int c = (idx >> 12) & 63;
  int pos = idx & (WH - 1);
  float m = mask[b * WH + pos];
  fm[idx] = fg[idx] * m + (1.f - m) * vmean[b * C + c];
}

// bgp[b][pos][c] = padded background + 1e-7
__global__ void k_bgpT(const float* __restrict__ fg, const float* __restrict__ mask,
                       float* __restrict__ bgp) {
  int b = blockIdx.y, xp = blockIdx.x;
  float* out = bgp + ((size_t)b * PP + (size_t)xp * PW) * C;
  int t = threadIdx.x;
  __shared__ float tile[64][65];
  int xi = xp - 1;
  if (xi >= 0 && xi < WD) {
    const float* fgb = fg + (size_t)b * C * WH + (size_t)xi * WD;
    const float* mkb = mask + (size_t)b * WH + (size_t)xi * WD;
    for (int i = t; i < 64 * 64; i += 256) {
      int c = i >> 6, y = i & 63;
      tile[c][y] = fgb[(size_t)c * WH + y] * (1.f - mkb[y]);
    }
  }
  __syncthreads();
  for (int i = t; i < PW * C; i += 256) {
    int yp = i >> 6, c = i & 63;
    float v = 1e-7f;
    int yj = yp - 1;
    if (xi >= 0 && xi < WD && yj >= 0 && yj < WD) v += tile[c][yj];
    out[(size_t)yp * C + c] = v;
  }
}

// Vg[b][pos][o] = Wv_p @ bgp[pos,:] + bv_p
__global__ void k_vgT(const float* __restrict__ bgp, const float* __restrict__ Wv_p,
                      const float* __restrict__ bv_p, float* __restrict__ Vg) {
  __shared__ float Wt[64][65];
  __shared__ float bgl[4][64];
  int t = threadIdx.x;
  for (int i = t; i < 4096; i += 256) Wt[i & 63][i >> 6] = Wv_p[i];
  int pos0 = blockIdx.x * 4;
  {
    int p2 = t >> 6, c = t & 63;
    int gp = pos0 + p2;
    bgl[p2][c] = (gp < BSZ * PP) ? bgp[(size_t)gp * C + c] : 0.f;
  }
  __syncthreads();
  int pi = t >> 6, o = t & 63;
  int gpos = pos0 + pi;
  if (gpos < BSZ * PP) {
    float acc = bv_p[o];
    for (int c = 0; c < 64; ++c) acc += Wt[c][o] * bgl[pi][c];
    Vg[(size_t)gpos * C + o] = acc;
  }
}

// mmf[b][n] = 1 if 3x3 mask window all zero
__global__ void k_mmf(const float* __restrict__ mask, float* __restrict__ mmf) {
  int idx = blockIdx.x * 256 + threadIdx.x;
  if (idx >= BSZ * NP) return;
  int b = idx >> 12, n = idx & 4095;
  int x = n >> 6, y = n & 63;
  float z = 0.f;
  for (int di = -1; di <= 1; ++di)
    for (int dj = -1; dj <= 1; ++dj) {
      int xi = x + di, yj = y + dj;
      if (xi >= 0 && xi < WD && yj >= 0 && yj < WD) z += mask[b * WH + xi * WD + yj];
    }
  mmf[idx] = (z == 0.f) ? 1.f : 0.f;
}

__global__ void k_scan(const float* __restrict__ mmf, int* __restrict__ lividx,
                       int* __restrict__ nliv) {
  int b = blockIdx.x, t = threadIdx.x;
  const float* mm = mmf + (size_t)b * NP;
  int* li = lividx + (size_t)b * NP;
  __shared__ int cnt[256];
  int loc[16];
  int c = 0;
#pragma unroll
  for (int i = 0; i < 16; ++i) {
    int lv = (mm[t * 16 + i] != 0.f) ? 1 : 0;
    loc[i] = lv;
    c += lv;
  }
  cnt[t] = c;
  __syncthreads();
  for (int s = 1; s < 256; s <<= 1) {
    int v = (t >= s) ? cnt[t - s] : 0;
    __syncthreads();
    cnt[t] += v;
    __syncthreads();
  }
  int base = cnt[t] - c;
#pragma unroll
  for (int i = 0; i < 16; ++i)
    if (loc[i]) li[base++] = t * 16 + i;
  int nl = cnt[255];
  if (t == 0) nliv[b] = nl;
  for (int i = nl + t; i < NP; i += 256) li[i] = 0;
}

// live-patch ck: (gamma/9)*Vg window, L2-normalized -> Akc hi/lo [nc][KC]
__global__ void k_ck(const float* __restrict__ Vg, const int* __restrict__ lividx,
                     const int* __restrict__ nliv, const float* __restrict__ gamma,
                     u16* __restrict__ AkcH, u16* __restrict__ AkcL) {
  int b = blockIdx.y, nc = blockIdx.x;
  if (nc >= nliv[b]) return;
  int n = lividx[(size_t)b * NP + nc];
  int x = n >> 6, y = n & 63;
  int c = threadIdx.x;
  const float* vg = Vg + (size_t)b * PP * C;
  float g9 = gamma[0] * (1.f / 9.f);
  float o[9];
  float ss = 0.f;
#pragma unroll
  for (int p = 0; p < 9; ++p) {
    int di = p / 3, dj = p % 3;
    float v = g9 * vg[(size_t)((x + di) * PW + (y + dj)) * C + c];
    o[p] = v;
    ss += v * v;
  }
#pragma unroll
  for (int off = 32; off > 0; off >>= 1) ss += __shfl_down(ss, off, 64);
  ss = __shfl(ss, 0, 64);
  float rn = 1.f / sqrtf(ss);
  u16* ph = AkcH + ((size_t)b * NP + nc) * KC + c * 9;
  u16* pl = AkcL + ((size_t)b * NP + nc) * KC + c * 9;
#pragma unroll
  for (int p = 0; p < 9; ++p) {
    u16 h, l;
    split2(o[p] * rn, h, l);
    ph[p] = h;
    pl[p] = l;
  }
}

// Akc [NP][KC] -> AkT [KC][NP] (hi/lo)
__global__ void k_trA(const u16* __restrict__ Sh, const u16* __restrict__ Sl,
                      u16* __restrict__ Dh, u16* __restrict__ Dl) {
  __shared__ __align__(16) u16 tile[64][72];
  int x0 = blockIdx.x * 64, k0 = blockIdx.y * 64;
  int t = threadIdx.x;
  for (int pass = 0; pass < 2; ++pass) {
    const u16* S = pass ? Sl : Sh;
    u16* D = pass ? Dl : Dh;
    for (int ch = t; ch < 512; ch += 256) {
      int r = ch >> 3, c0 = (ch & 7) * 8;
      *reinterpret_cast<uint4*>(&tile[r][c0]) =
          *reinterpret_cast<const uint4*>(S + (size_t)(x0 + r) * KC + k0 + c0);
    }
    __syncthreads();
    for (int ch = t; ch < 512; ch += 256) {
      int kr = ch >> 3, c0 = (ch & 7) * 8;
      union { u16 u[8]; uint4 v; } pk;
#pragma unroll
      for (int j = 0; j < 8; ++j) pk.u[j] = tile[c0 + j][kr];
      *reinterpret_cast<uint4*>(D + (size_t)(k0 + kr) * NP + x0 + c0) = pk.v;
    }
    __syncthreads();
  }
}

// im2col directly transposed + split: BimT hi/lo [xy][KC]
__global__ void k_im2colT(const float* __restrict__ fm, u16* __restrict__ base) {
  int ch = blockIdx.x * 256 + threadIdx.x;
  if (ch >= BSZ * WH * 72) return;
  int b = ch / (WH * 72);
  int rem = ch - b * WH * 72;
  int xy = rem / 72, kp = rem - xy * 72;
  int x = xy >> 6, y = xy & 63;
  union { u16 u[8]; uint4 v; } H, L;
#pragma unroll
  for (int j = 0; j < 8; ++j) {
    int k = kp * 8 + j;
    int c = k / 9, p = k - c * 9;
    int xi = x + p / 3 - 1, yj = y + p % 3 - 1;
    float v = 0.f;
    if (xi >= 0 && xi < WD && yj >= 0 && yj < WD)
      v = fm[((size_t)(b * C + c)) * WH + (xi << 6) + yj];
    split2(v, H.u[j], L.u[j]);
  }
  u16* bh = base + (size_t)b * 2 * WH * KC;
  u16* bl = bh + (size_t)WH * KC;
  *reinterpret_cast<uint4*>(bh + (size_t)xy * KC + kp * 8) = H.v;
  *reinterpret_cast<uint4*>(bl + (size_t)xy * KC + kp * 8) = L.v;
}

// ---------------- MFMA GEMMs ----------------

// gemm1: cr[m][n] = Akc[m][:] . BimT[n][:]   M-tile 128, N-tile 64, K=576
__global__ __launch_bounds__(256, 4) void k_gemmA(
    const u16* __restrict__ Ah, const u16* __restrict__ Al,
    const u16* __restrict__ Bh, const u16* __restrict__ Bl,
    const int* __restrict__ nliv, float* __restrict__ Cp) {
  int nl = *nliv;
  int m0 = blockIdx.y * 128;
  if (m0 >= nl) return;
  int n0 = blockIdx.x * 64;
  __shared__ __align__(16) u16 As[2][128][40];
  __shared__ __align__(16) u16 Bs[2][64][40];
  int t = threadIdx.x;
  f32x4 zero = {0.f, 0.f, 0.f, 0.f};
  f32x4 acc[2][4];
#pragma unroll
  for (int r = 0; r < 2; ++r)
#pragma unroll
    for (int c = 0; c < 4; ++c) acc[r][c] = zero;
  int l = t & 63, w = t >> 6;
  int lr = l & 15, lk = (l >> 4) * 8;
  for (int k0 = 0; k0 < KC; k0 += 32) {
    __syncthreads();
    for (int ch = t; ch < 1536; ch += 256) {
      const u16* src;
      u16* dst;
      if (ch < 1024) {
        int hl = ch >> 9, r = (ch >> 2) & 127, p = ch & 3;
        src = (hl ? Al : Ah) + (size_t)(m0 + r) * KC + k0 + p * 8;
        dst = &As[hl][r][p * 8];
      } else {
        int c2 = ch - 1024;
        int hl = c2 >> 8, r = (c2 >> 2) & 63, p = c2 & 3;
        src = (hl ? Bl : Bh) + (size_t)(n0 + r) * KC + k0 + p * 8;
        dst = &Bs[hl][r][p * 8];
      }
      *reinterpret_cast<uint4*>(dst) = *reinterpret_cast<const uint4*>(src);
    }
    __syncthreads();
    bf16x8 ah[2], al2[2], bh[4], bl2[4];
#pragma unroll
    for (int r = 0; r < 2; ++r) {
      ah[r] = *reinterpret_cast<const bf16x8*>(&As[0][32 * w + 16 * r + lr][lk]);
      al2[r] = *reinterpret_cast<const bf16x8*>(&As[1][32 * w + 16 * r + lr][lk]);
    }
#pragma unroll
    for (int c = 0; c < 4; ++c) {
      bh[c] = *reinterpret_cast<const bf16x8*>(&Bs[0][16 * c + lr][lk]);
      bl2[c] = *reinterpret_cast<const bf16x8*>(&Bs[1][16 * c + lr][lk]);
    }
#pragma unroll
    for (int r = 0; r < 2; ++r)
#pragma unroll
      for (int c = 0; c < 4; ++c) {
        acc[r][c] = __builtin_amdgcn_mfma_f32_16x16x32_bf16(ah[r], bh[c], acc[r][c], 0, 0, 0);
        acc[r][c] = __builtin_amdgcn_mfma_f32_16x16x32_bf16(ah[r], bl2[c], acc[r][c], 0, 0, 0);
        acc[r][c] = __builtin_amdgcn_mfma_f32_16x16x32_bf16(al2[r], bh[c], acc[r][c], 0, 0, 0);
      }
  }
#pragma unroll
  for (int r = 0; r < 2; ++r)
#pragma unroll
    for (int c = 0; c < 4; ++c)
#pragma unroll
      for (int q = 0; q < 4; ++q) {
        int row = m0 + 32 * w + 16 * r + ((l >> 4) << 2) + q;
        Cp[(size_t)row * WH + n0 + 16 * c + lr] = acc[r][c][q];
      }
}

// gemm2: P[m][n] = sum_k AkT[m][k] * att[k][n]; att packed (hi<<16|lo) u32.
__global__ __launch_bounds__(256, 4) void k_gemmB(
    const u16* __restrict__ Ah, const u16* __restrict__ Al,
    const u32* __restrict__ att32, const int* __restrict__ nliv,
    float* __restrict__ Cp) {
  int nl = *nliv;
  int Kend = (nl + 31) & ~31;
  int m0 = blockIdx.y * 64;
  int n0 = blockIdx.x * 64;
  __shared__ __align__(16) u16 As[2][64][40];
  __shared__ __align__(16) u16 Bs[2][64][40];
  __shared__ __align__(16) u32 Bfu[32][70];  // stride 70: 2-way-max bank aliasing
  int t = threadIdx.x;
  f32x4 zero = {0.f, 0.f, 0.f, 0.f};
  f32x4 acc[4];
#pragma unroll
  for (int c = 0; c < 4; ++c) acc[c] = zero;
  int l = t & 63, w = t >> 6;
  int lr = l & 15, lk = (l >> 4) * 8;
  for (int k0 = 0; k0 < Kend; k0 += 32) {
    __syncthreads();
    for (int ch = t; ch < 512; ch += 256) {
      int hl = ch >> 8, r = (ch >> 2) & 63, p = ch & 3;
      const u16* src = (hl ? Al : Ah) + (size_t)(m0 + r) * NP + k0 + p * 8;
      *reinterpret_cast<uint4*>(&As[hl][r][p * 8]) = *reinterpret_cast<const uint4*>(src);
    }
    {
      int r = t >> 3, c0 = (t & 7) * 8;
      int krow = k0 + r;
      uint4 w0 = {0u, 0u, 0u, 0u}, w1 = {0u, 0u, 0u, 0u};
      if (krow < nl) {
        const u32* bp = att32 + (size_t)krow * WH + n0 + c0;
        w0 = *reinterpret_cast<const uint4*>(bp);
        w1 = *reinterpret_cast<const uint4*>(bp + 4);
      }
      Bfu[r][c0 + 0] = w0.x; Bfu[r][c0 + 1] = w0.y;
      Bfu[r][c0 + 2] = w0.z; Bfu[r][c0 + 3] = w0.w;
      Bfu[r][c0 + 4] = w1.x; Bfu[r][c0 + 5] = w1.y;
      Bfu[r][c0 + 6] = w1.z; Bfu[r][c0 + 7] = w1.w;
    }
    __syncthreads();
    {
      int n = t >> 2, kq = (t & 3) * 8;
      union { u16 u[8]; uint4 v; } H, L;
#pragma unroll
      for (int j = 0; j < 8; ++j) {
        u32 v = Bfu[kq + j][n];
        H.u[j] = (u16)(v >> 16);
        L.u[j] = (u16)(v & 0xFFFFu);
      }
      *reinterpret_cast<uint4*>(&Bs[0][n][kq]) = H.v;
      *reinterpret_cast<uint4*>(&Bs[1][n][kq]) = L.v;
    }
    __syncthreads();
    bf16x8 ah, al2, bh[4], bl2[4];
    ah = *reinterpret_cast<const bf16x8*>(&As[0][16 * w + lr][lk]);
    al2 = *reinterpret_cast<const bf16x8*>(&As[1][16 * w + lr][lk]);
#pragma unroll
    for (int c = 0; c < 4; ++c) {
      bh[c] = *reinterpret_cast<const bf16x8*>(&Bs[0][16 * c + lr][lk]);
      bl2[c] = *reinterpret_cast<const bf16x8*>(&Bs[1][16 * c + lr][lk]);
    }
#pragma unroll
    for (int c = 0; c < 4; ++c) {
      acc[c] = __builtin_amdgcn_mfma_f32_16x16x32_bf16(ah, bh[c], acc[c], 0, 0, 0);
      acc[c] = __builtin_amdgcn_mfma_f32_16x16x32_bf16(ah, bl2[c], acc[c], 0, 0, 0);
      acc[c] = __builtin_amdgcn_mfma_f32_16x16x32_bf16(al2, bh[c], acc[c], 0, 0, 0);
    }
  }
#pragma unroll
  for (int c = 0; c < 4; ++c)
#pragma unroll
    for (int q = 0; q < 4; ++q) {
      int row = m0 + 16 * w + ((l >> 4) << 2) + q;
      Cp[(size_t)row * WH + n0 + 16 * c + lr] = acc[c][q];
    }
}

// ---------------- box / softmax / rec ----------------

__global__ __launch_bounds__(256) void k_box(const int* __restrict__ nliv,
                                             float* __restrict__ cr) {
  if ((int)blockIdx.x >= *nliv) return;
  __shared__ __align__(16) float sIn[WH];
  __shared__ __align__(16) float sT[WH];
  float* row = cr + (size_t)blockIdx.x * WH;
  const float4* r4 = reinterpret_cast<const float4*>(row);
  float4* s4 = reinterpret_cast<float4*>(sIn);
  for (int i = threadIdx.x; i < WH / 4; i += 256) s4[i] = r4[i];
  __syncthreads();
  for (int i = threadIdx.x; i < WH; i += 256) {
    int y = i & 63;
    float v = sIn[i];
    if (y > 0) v += sIn[i - 1];
    if (y < 63) v += sIn[i + 1];
    sT[i] = v;
  }
  __syncthreads();
  for (int i = threadIdx.x; i < WH; i += 256) {
    int x = i >> 6;
    float v = sT[i];
    if (x > 0) v += sT[i - 64];
    if (x < 63) v += sT[i + 64];
    row[i] = v;
  }
}

__global__ __launch_bounds__(256) void k_colstat(const float* __restrict__ cr,
                                                 const int* __restrict__ nliv,
                                                 float* __restrict__ pmax,
                                                 float* __restrict__ psum) {
  int xy = blockIdx.x * 256 + threadIdx.x;
  int nl = *nliv;
  int ns = (nl + 15) >> 4;
  int r0 = blockIdx.y * ns;
  int r1 = min(r0 + ns, nl);
  float mx = -3.4e38f, s = 0.f;
  for (int r = r0; r < r1; ++r) {
    float v = cr[(size_t)r * WH + xy];
    if (v <= mx) {
      s += __expf(v - mx);
    } else {
      s = s * __expf(mx - v) + 1.f;
      mx = v;
    }
  }
  pmax[blockIdx.y * WH + xy] = mx;
  psum[blockIdx.y * WH + xy] = s;
}

__global__ __launch_bounds__(256) void k_colmerge(const int* __restrict__ nliv,
                                                  const float* __restrict__ pmax,
                                                  const float* __restrict__ psum,
                                                  float* __restrict__ m2g,
                                                  float* __restrict__ invg) {
  int xy = blockIdx.x * 256 + threadIdx.x;
  int nl = *nliv;
  float M = -3.4e38f;
  for (int k = 0; k < 16; ++k) M = fmaxf(M, pmax[k * WH + xy]);
  float S = 0.f;
  if (M > -3.0e38f)
    for (int k = 0; k < 16; ++k) S += psum[k * WH + xy] * __expf(pmax[k * WH + xy] - M);
  int nm = NP - nl;
  float m2 = (nm > 0) ? fmaxf(M, 0.f) : M;
  float denom = (M > -3.0e38f ? S * __expf(M - m2) : 0.f) + (float)nm * __expf(-m2);
  m2g[xy] = m2;
  invg[xy] = 1.f / denom;
}

// apply: att = exp(v-m2)*inv, packed (bf16hi<<16)|bf16lo, in place over cr.
__global__ __launch_bounds__(256) void k_apply(const int* __restrict__ nliv,
                                               const float* __restrict__ m2g,
                                               const float* __restrict__ invg,
                                               float* __restrict__ cr) {
  int i = blockIdx.x * 256 + threadIdx.x;
  int row = i >> 10;
  int nl = *nliv;
  int kend = (nl + 31) & ~31;
  if (row >= kend) return;
  float4* p = reinterpret_cast<float4*>(cr) + i;
  uint4* po = reinterpret_cast<uint4*>(cr) + i;
  if (row >= nl) {
    *po = make_uint4(0u, 0u, 0u, 0u);
    return;
  }
  int xy = (i & 1023) << 2;
  float4 v = *p;
  const float4 m2 = *reinterpret_cast<const float4*>(m2g + xy);
  const float4 iv = *reinterpret_cast<const float4*>(invg + xy);
  uint4 o;
  o.x = pack2(__expf(v.x - m2.x) * iv.x);
  o.y = pack2(__expf(v.y - m2.y) * iv.y);
  o.z = pack2(__expf(v.z - m2.z) * iv.z);
  o.w = pack2(__expf(v.w - m2.w) * iv.w);
  *po = o;
}

__global__ void k_rec(const float* __restrict__ P, float* __restrict__ out) {
  int idx = blockIdx.x * 256 + threadIdx.x;
  if (idx >= BSZ * C * WH) return;
  int b = idx >> 18;
  int r = idx & 262143;
  int c = r >> 12;
  int xy = r & 4095;
  int x = xy >> 6, y = xy & 63;
  const float* Pb = P + (size_t)b * KC * WH;
  float acc = 0.f;
#pragma unroll
  for (int i = 0; i < 3; ++i) {
    int xp = x + 1 - i;
    if (xp < 0 || xp >= WD) continue;
#pragma unroll
    for (int j = 0; j < 3; ++j) {
      int yp = y + 1 - j;
      if (yp < 0 || yp >= WD) continue;
      acc += Pb[(size_t)(c * 9 + i * 3 + j) * WH + xp * WD + yp];
    }
  }
  out[idx] = acc;
}

// ---------------- launcher ----------------

extern "C" void kernel_launch(void* const* d_in, const int* in_sizes, int n_in,
                              void* d_out, int out_size, void* d_ws, size_t ws_size,
                              hipStream_t stream) {
  const float* fg    = (const float*)d_in[0];
  const float* mask  = (const float*)d_in[1];
  const float* Wv_f  = (const float*)d_in[7];
  const float* bv_f  = (const float*)d_in[8];
  const float* Wv_p  = (const float*)d_in[13];
  const float* bv_p  = (const float*)d_in[14];
  const float* gamma = (const float*)d_in[15];

  float* ws = (float*)d_ws;
  size_t off = 0;
  auto alloc = [&](size_t n) { size_t o = off; off += (n + 63) & ~(size_t)63; return o; };
  u16* AkcH = (u16*)(ws + alloc((size_t)BSZ * NP * KC / 2));
  u16* AkcL = (u16*)(ws + alloc((size_t)BSZ * NP * KC / 2));
  u16* AkTH = (u16*)(ws + alloc((size_t)KC * NP / 2));
  u16* AkTL = (u16*)(ws + alloc((size_t)KC * NP / 2));
  float* BimTPb = ws + alloc((size_t)BSZ * KC * WH);  // per-sample: [hi|lo] shorts == Pb f32
  float* mmf  = ws + alloc((size_t)BSZ * NP);
  int* lividx = (int*)(ws + alloc((size_t)BSZ * NP));
  int* nliv   = (int*)(ws + alloc(64));
  float* mu   = ws + alloc(BSZ * C);
  float* vmn  = ws + alloc(BSZ * C);
  float* pmax = ws + alloc((size_t)16 * WH);
  float* psum = ws + alloc((size_t)16 * WH);
  float* m2g  = ws + alloc(WH);
  float* invg = ws + alloc(WH);
  float* cr   = ws + alloc((size_t)NP * WH);  // single sample; att32 packs in place
  size_t poff = 0;
  auto palloc = [&](size_t n) { size_t o = poff; poff += (n + 63) & ~(size_t)63; return o; };
  float* bgp = cr + palloc((size_t)BSZ * PP * C);
  float* Vg  = cr + palloc((size_t)BSZ * PP * C);
  float* fmb = cr + palloc((size_t)BSZ * C * WH);
  (void)ws_size; (void)in_sizes; (void)n_in; (void)out_size;

  k_mu<<<BSZ * C, 256, 0, stream>>>(fg, mask, mu);
  k_vmean<<<1, 128, 0, stream>>>(Wv_f, bv_f, mu, vmn);
  k_fm<<<(BSZ * C * WH + 255) / 256, 256, 0, stream>>>(fg, mask, vmn, fmb);
  k_bgpT<<<dim3(PW, BSZ), 256, 0, stream>>>(fg, mask, bgp);
  k_vgT<<<(BSZ * PP + 3) / 4, 256, 0, stream>>>(bgp, Wv_p, bv_p, Vg);
  k_mmf<<<(BSZ * NP + 255) / 256, 256, 0, stream>>>(mask, mmf);
  k_scan<<<BSZ, 256, 0, stream>>>(mmf, lividx, nliv);
  k_ck<<<dim3(NP, BSZ), 64, 0, stream>>>(Vg, lividx, nliv, gamma, AkcH, AkcL);
  k_im2colT<<<(BSZ * WH * 72 + 255) / 256, 256, 0, stream>>>(fmb, (u16*)BimTPb);

  for (int b = 0; b < BSZ; ++b) {
    const u16* AkcHb = AkcH + (size_t)b * NP * KC;
    const u16* AkcLb = AkcL + (size_t)b * NP * KC;
    const u16* BimTh = (const u16*)BimTPb + (size_t)b * 2 * WH * KC;
    const u16* BimTl = BimTh + (size_t)WH * KC;
    float* Pb = BimTPb + (size_t)b * KC * WH;
    const int* nlb = nliv + b;
    k_trA<<<dim3(NP / 64, KC / 64), 256, 0, stream>>>(AkcHb, AkcLb, AkTH, AkTL);
    k_gemmA<<<dim3(WH / 64, NP / 128), 256, 0, stream>>>(AkcHb, AkcLb, BimTh, BimTl,
                                                         nlb, cr);
    k_box<<<NP, 256, 0, stream>>>(nlb, cr);
    k_colstat<<<dim3(WH / 256, 16), 256, 0, stream>>>(cr, nlb, pmax, psum);
    k_colmerge<<<WH / 256, 256, 0, stream>>>(nlb, pmax, psum, m2g, invg);
    k_apply<<<NP * (WH / 4) / 256, 256, 0, stream>>>(nlb, m2g, invg, cr);
    k_gemmB<<<dim3(WH / 64, KC / 64), 256, 0, stream>>>(AkTH, AkTL, (const u32*)cr,
                                                        nlb, Pb);
  }
  k_rec<<<(BSZ * C * WH + 255) / 256, 256, 0, stream>>>(BimTPb, (float*)d_out);
}